// Round 14
// baseline (262.627 us; speedup 1.0000x reference)
//
#include <hip/hip_runtime.h>
#include <hip/hip_bf16.h>
#include <cstdint>
#include <cstddef>

#define DEV __device__ __forceinline__

// problem constants: B=128, S=512, V=30000, DS=64, DF=300, H=600, BB=256

typedef __attribute__((ext_vector_type(8))) short bf16x8;
typedef __attribute__((ext_vector_type(4))) float f32x4;

DEV float geluf(float x){ return 0.5f*x*(1.f + erff(x*0.7071067811865475f)); }
DEV float gelu_fast(float x){
  float x2 = x*x;
  float e = __builtin_amdgcn_exp2f(x * __builtin_fmaf(x2, -0.102953f, -2.302218f));
  return x * __builtin_amdgcn_rcpf(1.f + e);
}

DEV float wave_sum(float v){
  v += __shfl_xor(v, 1); v += __shfl_xor(v, 2); v += __shfl_xor(v, 4);
  v += __shfl_xor(v, 8); v += __shfl_xor(v, 16); v += __shfl_xor(v, 32);
  return v;
}
DEV float wave_max(float v){
  v = fmaxf(v, __shfl_xor(v, 1)); v = fmaxf(v, __shfl_xor(v, 2));
  v = fmaxf(v, __shfl_xor(v, 4)); v = fmaxf(v, __shfl_xor(v, 8));
  v = fmaxf(v, __shfl_xor(v, 16)); v = fmaxf(v, __shfl_xor(v, 32));
  return v;
}
// 512-thread block sum via wave shuffles + 8-slot LDS (2 barriers)
DEV float blk_sum512w(float* red8, int t, float v){
  float w = wave_sum(v);
  if ((t & 63) == 0) red8[t >> 6] = w;
  __syncthreads();
  float r = (red8[0] + red8[1]) + (red8[2] + red8[3])
          + (red8[4] + red8[5]) + (red8[6] + red8[7]);
  __syncthreads();
  return r;
}
DEV float blk_max512w(float* red8, int t, float v){
  float w = wave_max(v);
  if ((t & 63) == 0) red8[t >> 6] = w;
  __syncthreads();
  float r = fmaxf(fmaxf(fmaxf(red8[0], red8[1]), fmaxf(red8[2], red8[3])),
                  fmaxf(fmaxf(red8[4], red8[5]), fmaxf(red8[6], red8[7])));
  __syncthreads();
  return r;
}
DEV float blk_sum256(float* red, int t, float v){
  red[t] = v; __syncthreads();
  for (int o = 128; o > 0; o >>= 1){ if (t < o) red[t] += red[t+o]; __syncthreads(); }
  float r = red[0]; __syncthreads(); return r;
}

DEV ushort f2bf(float v){ __hip_bfloat16 h = __float2bfloat16(v); return *(ushort*)&h; }
DEV float bf2f(ushort u){ __hip_bfloat16 h; *(ushort*)&h = u; return __bfloat162float(h); }

// ---- mask dtype classifier ----
DEV int mask_mode(const unsigned char* m){
  bool big = false, off123 = false, off0one = false;
  #pragma unroll
  for (int i = 0; i < 16; ++i){
    unsigned char c = m[i];
    if (c > 1) big = true;
    if ((i & 3) != 0 && c != 0) off123 = true;
    if ((i & 3) == 0 && c == 1) off0one = true;
  }
  if (big) return 2;
  if (!off123 && off0one) return 1;
  return 0;
}
DEV float mask_read(const void* m, int idx, int mode){
  if (mode == 1) return ((const int*)m)[idx] ? 1.f : 0.f;
  if (mode == 2) return ((const unsigned short*)m)[idx] ? 1.f : 0.f;
  return ((const unsigned char*)m)[idx] ? 1.f : 0.f;
}

// ---------------- fused: pack A + per-vocab stats ----------------
__global__ __launch_bounds__(256)
void k_pack_stats(const float* __restrict__ feat, ushort* __restrict__ A,
                  float* __restrict__ fsum, float* __restrict__ fsq){
  int v = blockIdx.x*4 + (threadIdx.x >> 6);
  int ln = threadIdx.x & 63;
  if (v >= 30080) return;
  float vals[8] = {0.f,0.f,0.f,0.f,0.f,0.f,0.f,0.f};
  if (v < 30000 && ln < 38){
    const float* fr = &feat[(size_t)v*300];
    if (ln < 37){
      float4 a = *(const float4*)&fr[ln*8];
      float4 b = *(const float4*)&fr[ln*8 + 4];
      vals[0]=a.x; vals[1]=a.y; vals[2]=a.z; vals[3]=a.w;
      vals[4]=b.x; vals[5]=b.y; vals[6]=b.z; vals[7]=b.w;
    } else {
      float4 a = *(const float4*)&fr[296];
      vals[0]=a.x; vals[1]=a.y; vals[2]=a.z; vals[3]=a.w;
    }
  }
  if (ln < 40){
    union { ushort u[8]; bf16x8 v8; } pk;
    #pragma unroll
    for (int i = 0; i < 8; ++i) pk.u[i] = f2bf(vals[i]);
    *(bf16x8*)&A[(size_t)v*320 + ln*8] = pk.v8;
  }
  float s = 0.f, q = 0.f;
  #pragma unroll
  for (int i = 0; i < 8; ++i){ s += vals[i]; q += vals[i]*vals[i]; }
  for (int o = 32; o > 0; o >>= 1){ s += __shfl_xor(s, o); q += __shfl_xor(q, o); }
  if (ln == 0 && v < 30000){ fsum[v] = s; fsq[v] = q; }
}

// ---------------- fused gw: gw_g[j]=sum_i g[i]*w1[i,j]; c_g[j]=sum_i bln[i]*w1[i,j] + b1[j] ----------------
__global__ __launch_bounds__(256)
void k_gw(const float* __restrict__ w1, const float* __restrict__ g,
          const float* __restrict__ bln, const float* __restrict__ b1,
          float* __restrict__ gw_g, float* __restrict__ c_g){
  int j = blockIdx.x*256 + threadIdx.x;
  if (j >= 600) return;
  float a = 0.f, c = 0.f;
  for (int i = 0; i < 600; ++i){
    float w = w1[(size_t)i*600 + j];
    a += g[i]*w; c += bln[i]*w;
  }
  gw_g[j] = a; c_g[j] = c + b1[j];
}

// ---------------- pack B^T ----------------
__global__ __launch_bounds__(256)
void k_pack_b(const float* __restrict__ w1, const float* __restrict__ g, ushort* __restrict__ BT){
  int id = blockIdx.x*256 + threadIdx.x;
  if (id >= 640*320) return;
  int n = id % 640, k = id / 640;
  float val = (k < 300 && n < 600) ? g[k]*w1[k*600 + n] : 0.f;
  BT[(size_t)n*320 + k] = f2bf(val);
}

// ---------------- P1: U GEMM (MFMA) ----------------
__global__ __launch_bounds__(256)
void k_ugemm_mfma(const ushort* __restrict__ A, const ushort* __restrict__ BT,
                  __hip_bfloat16* __restrict__ U){
  __shared__ ushort As[128][40];
  __shared__ ushort Bs[128][40];
  int tid = threadIdx.x;
  int bm = blockIdx.x * 128, bn = blockIdx.y * 128;
  int wid = tid >> 6, lane = tid & 63;
  int wr = wid >> 1, wc = wid & 1;
  int lr = lane & 15, lk = lane >> 4;
  f32x4 acc[4][4] = {};
  for (int k0 = 0; k0 < 320; k0 += 32){
    #pragma unroll
    for (int j = 0; j < 2; ++j){
      int idx = tid + 256*j;
      int row = idx >> 2, ko = (idx & 3)*8;
      *(bf16x8*)&As[row][ko] = *(const bf16x8*)&A[(size_t)(bm+row)*320 + k0 + ko];
      *(bf16x8*)&Bs[row][ko] = *(const bf16x8*)&BT[(size_t)(bn+row)*320 + k0 + ko];
    }
    __syncthreads();
    bf16x8 af[4], bfr[4];
    #pragma unroll
    for (int f = 0; f < 4; ++f){
      af[f]  = *(const bf16x8*)&As[wr*64 + f*16 + lr][lk*8];
      bfr[f] = *(const bf16x8*)&Bs[wc*64 + f*16 + lr][lk*8];
    }
    #pragma unroll
    for (int i = 0; i < 4; ++i)
      #pragma unroll
      for (int j = 0; j < 4; ++j)
        acc[i][j] = __builtin_amdgcn_mfma_f32_16x16x32_bf16(af[i], bfr[j], acc[i][j], 0, 0, 0);
    __syncthreads();
  }
  #pragma unroll
  for (int i = 0; i < 4; ++i){
    #pragma unroll
    for (int j = 0; j < 4; ++j){
      #pragma unroll
      for (int r = 0; r < 4; ++r){
        int row = bm + wr*64 + i*16 + lk*4 + r;
        int col = bn + wc*64 + j*16 + lr;
        if (row < 30000 && col < 600)
          U[(size_t)row*600 + col] = __float2bfloat16(acc[i][j][r]);
      }
    }
  }
}

// ---------------- S1a: mu gather+stage ----------------
__global__ __launch_bounds__(256)
void k_mu_stage(const int* __restrict__ ids_a, const void* __restrict__ mask_a,
                const int* __restrict__ ids_b, const void* __restrict__ mask_b,
                const float* __restrict__ mu_tab, const float* __restrict__ pos_mu,
                const float* __restrict__ alpha_tab, const float* __restrict__ pos_alpha,
                ushort* __restrict__ MuS, float* __restrict__ cent_p,
                float* __restrict__ msum_p, float* __restrict__ al_g){
  int blk = blockIdx.x;
  int bb = blk >> 3, qr = blk & 7;
  int b = bb & 127;
  const int* ids = (bb < 128) ? ids_a : ids_b;
  const void* msk = (bb < 128) ? mask_a : mask_b;
  int t = threadIdx.x;
  int grp = t >> 4, sub = t & 15;
  __shared__ int mmode_s;
  __shared__ float gpart[16][64];
  __shared__ float mf_s[64];
  __shared__ float red[256];
  if (t == 0) mmode_s = mask_mode((const unsigned char*)msk);
  __syncthreads();
  int mmode = mmode_s;
  float cp0=0.f, cp1=0.f, cp2=0.f, cp3=0.f;
  #pragma unroll
  for (int k = 0; k < 4; ++k){
    int sl = grp*4 + k;
    int s  = qr*64 + sl;
    int id = ids[b*512 + s];
    float mf = mask_read(msk, b*512 + s, mmode);
    float4 m4 = *(const float4*)&mu_tab[(size_t)id*64 + sub*4];
    float4 p4 = *(const float4*)&pos_mu[s*64 + sub*4];
    float v0 = m4.x+p4.x, v1 = m4.y+p4.y, v2 = m4.z+p4.z, v3 = m4.w+p4.w;
    ushort4 st; st.x = f2bf(v0); st.y = f2bf(v1); st.z = f2bf(v2); st.w = f2bf(v3);
    *(ushort4*)&MuS[((size_t)bb*512 + s)*64 + sub*4] = st;
    cp0 += mf*v0; cp1 += mf*v1; cp2 += mf*v2; cp3 += mf*v3;
    if (sub == 0){
      mf_s[sl] = mf;
      float pa = pos_alpha[s];
      float sg = __builtin_amdgcn_rcpf(1.f + __builtin_amdgcn_exp2f(-1.44269504f*pa));
      al_g[bb*512 + s] = alpha_tab[id] * sg * mf;
    }
  }
  gpart[grp][sub*4+0] = cp0; gpart[grp][sub*4+1] = cp1;
  gpart[grp][sub*4+2] = cp2; gpart[grp][sub*4+3] = cp3;
  __syncthreads();
  if (t < 64){
    float c = 0.f;
    #pragma unroll
    for (int g = 0; g < 16; ++g) c += gpart[g][t];
    cent_p[(size_t)blk*64 + t] = c;
  }
  float ms = blk_sum256(red, t, (t < 64) ? mf_s[t] : 0.f);
  if (t == 0) msum_p[blk] = ms;
}

// ---------------- S1c: cent reduce (fused) + w = alpha*K + render partials ----------------
__global__ __launch_bounds__(256)
void k_wrender(const int* __restrict__ ids_a, const int* __restrict__ ids_b,
               const float* __restrict__ logvar_tab, const ushort* __restrict__ MuS,
               const float* __restrict__ cent_p, const float* __restrict__ msum_p,
               const float* __restrict__ al_g,
               const float* __restrict__ log_tau, const ushort* __restrict__ Abf,
               float* __restrict__ wsum_p, float* __restrict__ sgs_p){
  int blk = blockIdx.x;
  int bb = blk >> 3, qr = blk & 7;
  int b = bb & 127;
  const int* ids = (bb < 128) ? ids_a : ids_b;
  int t = threadIdx.x;
  int grp = t >> 4, sub = t & 15;
  __shared__ float cent_s[64];
  __shared__ float wl[64];
  __shared__ int   idl[64];
  __shared__ float pacc[4][304];
  __shared__ float red[256];
  // fused centroid reduce (redundant per block, trivial)
  if (t < 64){
    float c = 0.f, ms = 0.f;
    #pragma unroll
    for (int q = 0; q < 8; ++q){
      c  += cent_p[(size_t)(bb*8+q)*64 + t];
      ms += msum_p[bb*8+q];
    }
    cent_s[t] = c / fmaxf(ms, 1.f);
  }
  __syncthreads();
  float itau = __builtin_amdgcn_exp2f(-1.44269504f*log_tau[0]);
  float c0 = cent_s[sub*4+0], c1 = cent_s[sub*4+1];
  float c2 = cent_s[sub*4+2], c3 = cent_s[sub*4+3];
  #pragma unroll
  for (int k = 0; k < 4; ++k){
    int sl = grp*4 + k, s = qr*64 + sl;
    int id = ids[b*512 + s];
    float4 lv = *(const float4*)&logvar_tab[(size_t)id*64 + sub*4];
    float iv0 = __builtin_amdgcn_exp2f(-1.44269504f*lv.x);
    float iv1 = __builtin_amdgcn_exp2f(-1.44269504f*lv.y);
    float iv2 = __builtin_amdgcn_exp2f(-1.44269504f*lv.z);
    float iv3 = __builtin_amdgcn_exp2f(-1.44269504f*lv.w);
    ushort4 mu = *(const ushort4*)&MuS[((size_t)bb*512 + s)*64 + sub*4];
    float d0 = bf2f(mu.x)-c0, d1 = bf2f(mu.y)-c1, d2v = bf2f(mu.z)-c2, d3 = bf2f(mu.w)-c3;
    float val = d0*d0*iv0 + d1*d1*iv1 + d2v*d2v*iv2 + d3*d3*iv3;
    val += __shfl_xor(val, 1); val += __shfl_xor(val, 2);
    val += __shfl_xor(val, 4); val += __shfl_xor(val, 8);
    if (sub == 0){
      idl[sl] = id;
      float K = __builtin_amdgcn_exp2f(-0.72134752f * val * itau);
      wl[sl] = al_g[bb*512 + s] * K;
    }
  }
  __syncthreads();
  float ws = blk_sum256(red, t, (t < 64) ? wl[t] : 0.f);
  if (t == 0) wsum_p[blk] = ws;
  int wv = t >> 6, ln = t & 63;
  if (ln < 38){
    float a[8] = {};
    for (int k = 0; k < 16; ++k){
      int sl = (wv << 4) | k;
      float w = wl[sl];
      bf16x8 f8 = *(const bf16x8*)&Abf[(size_t)idl[sl]*320 + ln*8];
      #pragma unroll
      for (int r = 0; r < 8; ++r) a[r] += w * bf2f((ushort)f8[r]);
    }
    #pragma unroll
    for (int r = 0; r < 8; ++r) pacc[wv][ln*8 + r] = a[r];
  }
  __syncthreads();
  for (int j = t; j < 300; j += 256)
    sgs_p[(size_t)blk*304 + j] = pacc[0][j] + pacc[1][j] + pacc[2][j] + pacc[3][j];
}

// ---------------- S1d: sgs reduce, query, scores, softmax (wave reductions) ----------------
__global__ __launch_bounds__(512)
void k_stage1c(const int* __restrict__ ids_a, const void* __restrict__ mask_a,
               const int* __restrict__ ids_b, const void* __restrict__ mask_b,
               const ushort* __restrict__ MuS, const float* __restrict__ sgs_p,
               const float* __restrict__ wsum_p,
               const float* __restrict__ wq, const float* __restrict__ bq,
               const float* __restrict__ wk, const float* __restrict__ bk,
               float* __restrict__ sgs_g, float* __restrict__ ssum_g, float* __restrict__ ssq_g,
               float* __restrict__ wgt_g)
{
  int bb = blockIdx.x;
  const void* msk = (bb < 128) ? mask_a : mask_b;
  int b = bb & 127;
  int t = threadIdx.x;
  __shared__ float mf_l[512], w_l[512];
  __shared__ float red8[8], red8b[8];
  __shared__ float q_l[64], qk_l[64];
  __shared__ float sgs_l[304];
  __shared__ float bkq_s;
  __shared__ int mmode;
  if (t == 0) mmode = mask_mode((const unsigned char*)msk);
  __syncthreads();
  mf_l[t] = mask_read(msk, b*512 + t, mmode);

  float wsum = 0.f;
  #pragma unroll
  for (int q = 0; q < 8; ++q) wsum += wsum_p[bb*8 + q];
  wsum = fmaxf(wsum, 1e-8f);
  if (t < 300){
    float sa = 0.f;
    #pragma unroll
    for (int q = 0; q < 8; ++q) sa += sgs_p[(size_t)(bb*8+q)*304 + t];
    float sv = sa / wsum;
    sgs_l[t] = sv;
    sgs_g[bb*300 + t] = sv;
  }
  __syncthreads();
  {
    float v1 = (t < 300) ? sgs_l[t] : 0.f;
    float s1 = wave_sum(v1), s2 = wave_sum(v1*v1);
    if ((t & 63) == 0){ red8[t >> 6] = s1; red8b[t >> 6] = s2; }
    __syncthreads();
    if (t == 0){
      float ssum = (red8[0]+red8[1])+(red8[2]+red8[3])+(red8[4]+red8[5])+(red8[6]+red8[7]);
      float ssq  = (red8b[0]+red8b[1])+(red8b[2]+red8b[3])+(red8b[4]+red8b[5])+(red8b[6]+red8b[7]);
      ssum_g[bb] = ssum; ssq_g[bb] = ssq;
    }
  }

  if (t < 64){
    float q = bq[t];
    for (int i = 0; i < 300; ++i) q += sgs_l[i]*wq[i*64 + t];
    q_l[t] = q;
  }
  __syncthreads();
  if (t < 64){
    float a = 0.f;
    for (int j = 0; j < 64; ++j) a += wk[t*64 + j]*q_l[j];
    qk_l[t] = a;
  }
  if (t == 0){
    float s = 0.f;
    for (int j = 0; j < 64; ++j) s += bk[j]*q_l[j];
    bkq_s = s;
  }
  __syncthreads();

  int grp = t >> 4, sub = t & 15;
  {
    float q0 = qk_l[sub*4+0], q1 = qk_l[sub*4+1], q2 = qk_l[sub*4+2], q3 = qk_l[sub*4+3];
    for (int k = 0; k < 16; ++k){
      int s = (grp << 4) | k;
      ushort4 mu = *(const ushort4*)&MuS[((size_t)bb*512 + s)*64 + sub*4];
      float val = bf2f(mu.x)*q0 + bf2f(mu.y)*q1 + bf2f(mu.z)*q2 + bf2f(mu.w)*q3;
      val += __shfl_xor(val, 1); val += __shfl_xor(val, 2);
      val += __shfl_xor(val, 4); val += __shfl_xor(val, 8);
      if (sub == 0){
        float sv = (val + bkq_s) * 0.125f;
        w_l[s] = (mf_l[s] != 0.f) ? sv : -1e30f;
      }
    }
  }
  __syncthreads();

  float mx = blk_max512w(red8, t, w_l[t]);
  float ex = __expf(w_l[t] - mx);
  float Z  = blk_sum512w(red8, t, ex);
  wgt_g[bb*512 + t] = ex / Z;
}

// ---------------- k_vgemm2 ----------------
__global__ __launch_bounds__(256)
void k_vgemm2(const float* __restrict__ sgs, const float* __restrict__ w1,
              const float* __restrict__ ln1g, float* __restrict__ V_g){
  __shared__ float As[32][33], Bs[32][33];
  int t = threadIdx.x;
  int bm = blockIdx.x*32, bn = blockIdx.y*32;
  int tx = t & 15, ty = t >> 4;
  float a00=0.f,a01=0.f,a10=0.f,a11=0.f;
  for (int k0 = 0; k0 < 300; k0 += 32){
    #pragma unroll
    for (int i = 0; i < 4; ++i){
      int idx = t + i*256;
      int kk = idx & 31, m = idx >> 5;
      int kg = k0 + kk;
      As[kk][m] = (kg < 300) ? sgs[(size_t)(bm+m)*300 + kg] : 0.f;
    }
    #pragma unroll
    for (int i = 0; i < 4; ++i){
      int idx = t + i*256;
      int n = idx & 31, kk = idx >> 5;
      int kg = k0 + kk, cg = bn + n;
      Bs[kk][n] = (kg < 300 && cg < 600) ? ln1g[300 + kg]*w1[(size_t)(300 + kg)*600 + cg] : 0.f;
    }
    __syncthreads();
    #pragma unroll
    for (int kk = 0; kk < 32; ++kk){
      float x0 = As[kk][ty*2], x1 = As[kk][ty*2+1];
      float y0 = Bs[kk][tx*2], y1 = Bs[kk][tx*2+1];
      a00 += x0*y0; a01 += x0*y1; a10 += x1*y0; a11 += x1*y1;
    }
    __syncthreads();
  }
  int r0 = bm + ty*2, c0 = bn + tx*2;
  #pragma unroll
  for (int i = 0; i < 2; ++i){
    #pragma unroll
    for (int j = 0; j < 2; ++j){
      int r = r0 + i, c = c0 + j;
      if (c < 600) V_g[(size_t)r*600 + c] = (i==0 ? (j==0?a00:a01) : (j==0?a10:a11));
    }
  }
}

// ---------------- K2: hbar + Fbar eighth-split (balanced tail) ----------------
__global__ __launch_bounds__(256)
void k_hbar_fbar(const int* __restrict__ ids_a, const int* __restrict__ ids_b,
                 const __hip_bfloat16* __restrict__ U, const ushort* __restrict__ Abf,
                 const float* __restrict__ fsum, const float* __restrict__ fsq,
                 const float* __restrict__ ssum_g, const float* __restrict__ ssq_g,
                 const float* __restrict__ V_g, const float* __restrict__ gw_g,
                 const float* __restrict__ c_g, const float* __restrict__ wgt_g,
                 float* __restrict__ hbar_p, float* __restrict__ Fbar_p)
{
  int blk = blockIdx.x;
  int bb = blk >> 3, qr = blk & 7;
  int b = bb & 127;
  const int* ids = (bb < 128) ? ids_a : ids_b;
  int t = threadIdx.x;
  __shared__ int id_l[64];
  __shared__ float m_l[64], rs_l[64], wg_l[64];
  __shared__ float hp[4][600];
  __shared__ float fp[4][304];
  float ss = ssum_g[bb], sq = ssq_g[bb];
  if (t < 64){
    int s = qr*64 + t;
    int id = ids[b*512 + s];
    id_l[t] = id;
    float m = (fsum[id] + ss) * (1.f/600.f);
    float var = (fsq[id] + sq) * (1.f/600.f) - m*m;
    m_l[t] = m;
    rs_l[t] = 1.f / sqrtf(var + 1e-5f);
    wg_l[t] = wgt_g[bb*512 + s];
  }
  __syncthreads();

  int wv = t >> 6, ln = t & 63;
  float Vp[8], gwp[8], cp[8];
  #pragma unroll
  for (int r = 0; r < 8; ++r){
    int j = ln*8 + r;
    Vp[r] = V_g[bb*600 + j]; gwp[r] = gw_g[j]; cp[r] = c_g[j];
  }
  float Vs[4] = {}, gws[4] = {}, cs[4] = {};
  if (ln < 22){
    #pragma unroll
    for (int r = 0; r < 4; ++r){
      int j = 512 + ln*4 + r;
      Vs[r] = V_g[bb*600 + j]; gws[r] = gw_g[j]; cs[r] = c_g[j];
    }
  }
  float h1[8] = {}, h2[4] = {}, fa[8] = {};

  for (int k = 0; k < 16; ++k){
    int s = (wv << 4) | k;
    int id = id_l[s];
    float w = wg_l[s], m = m_l[s], rs = rs_l[s];
    const __hip_bfloat16* ur = &U[(size_t)id*600];
    bf16x8 u8 = *(const bf16x8*)&ur[ln*8];
    #pragma unroll
    for (int r = 0; r < 8; ++r){
      float u = bf2f((ushort)u8[r]);
      float a = (u + Vp[r] - m*gwp[r])*rs + cp[r];
      h1[r] += w*gelu_fast(a);
    }
    if (ln < 22){
      ushort4 u4 = *(const ushort4*)&ur[512 + ln*4];
      float uu[4] = { bf2f(u4.x), bf2f(u4.y), bf2f(u4.z), bf2f(u4.w) };
      #pragma unroll
      for (int r = 0; r < 4; ++r){
        float a = (uu[r] + Vs[r] - m*gws[r])*rs + cs[r];
        h2[r] += w*gelu_fast(a);
      }
    }
    if (ln < 38){
      bf16x8 f8 = *(const bf16x8*)&Abf[(size_t)id*320 + ln*8];
      #pragma unroll
      for (int r = 0; r < 8; ++r) fa[r] += w * bf2f((ushort)f8[r]);
    }
  }
  #pragma unroll
  for (int r = 0; r < 8; ++r) hp[wv][ln*8 + r] = h1[r];
  if (ln < 22){
    #pragma unroll
    for (int r = 0; r < 4; ++r) hp[wv][512 + ln*4 + r] = h2[r];
  }
  if (ln < 38){
    #pragma unroll
    for (int r = 0; r < 8; ++r) fp[wv][ln*8 + r] = fa[r];
  }
  __syncthreads();
  size_t hbase = ((size_t)qr*256 + bb)*608;
  for (int j = t; j < 600; j += 256){
    hbar_p[hbase + j] = hp[0][j] + hp[1][j] + hp[2][j] + hp[3][j];
  }
  if (t < 8) hbar_p[hbase + 600 + t] = 0.f;
  size_t fbase = ((size_t)qr*256 + bb)*300;
  for (int j = t; j < 300; j += 256){
    Fbar_p[fbase + j] = fp[0][j] + fp[1][j] + fp[2][j] + fp[3][j];
  }
}

// ---------------- k_hreduce ----------------
__global__ __launch_bounds__(256)
void k_hreduce(const float* __restrict__ hbar_p, const float* __restrict__ Fbar_p,
               float* __restrict__ hbar_s, float* __restrict__ Fbar_s){
  int i = blockIdx.x*256 + threadIdx.x;
  const size_t Q  = (size_t)256*608;
  const size_t QF = (size_t)256*300;
  if (i < 256*608){
    float s0 = hbar_p[i]       + hbar_p[Q + i];
    float s1 = hbar_p[2*Q + i] + hbar_p[3*Q + i];
    float s2 = hbar_p[4*Q + i] + hbar_p[5*Q + i];
    float s3 = hbar_p[6*Q + i] + hbar_p[7*Q + i];
    hbar_s[i] = (s0 + s1) + (s2 + s3);
  }
  if (i < 256*300){
    float s0 = Fbar_p[i]        + Fbar_p[QF + i];
    float s1 = Fbar_p[2*QF + i] + Fbar_p[3*QF + i];
    float s2 = Fbar_p[4*QF + i] + Fbar_p[5*QF + i];
    float s3 = Fbar_p[6*QF + i] + Fbar_p[7*QF + i];
    Fbar_s[i] = (s0 + s1) + (s2 + s3);
  }
}

// ============ final chain: split-K tiled fp32 GEMMs ============

__global__ __launch_bounds__(256)
void k_att_sk(const float* __restrict__ hbar_s, const float* __restrict__ w2,
              float* __restrict__ att_p){
  __shared__ float As[32][33], Bs[32][33];
  int t = threadIdx.x;
  int bm = blockIdx.x*32, bn = blockIdx.y*32, kc = blockIdx.z;
  int tx = t & 15, ty = t >> 4;
  int kbeg = kc*160, kend = (kc == 3) ? 608 : kbeg + 160;
  float a00=0.f,a01=0.f,a10=0.f,a11=0.f;
  for (int k0 = kbeg; k0 < kend; k0 += 32){
    #pragma unroll
    for (int i = 0; i < 4; ++i){
      int idx = t + i*256;
      int kk = idx & 31, m = idx >> 5;
      As[kk][m] = hbar_s[(size_t)(bm+m)*608 + k0 + kk];
    }
    #pragma unroll
    for (int i = 0; i < 4; ++i){
      int idx = t + i*256;
      int n = idx & 31, kk = idx >> 5;
      int kg = k0 + kk, cg = bn + n;
      Bs[kk][n] = (kg < 600 && cg < 300) ? w2[(size_t)kg*300 + cg] : 0.f;
    }
    __syncthreads();
    #pragma unroll
    for (int kk = 0; kk < 32; ++kk){
      float x0 = As[kk][ty*2], x1 = As[kk][ty*2+1];
      float y0 = Bs[kk][tx*2], y1 = Bs[kk][tx*2+1];
      a00 += x0*y0; a01 += x0*y1; a10 += x1*y0; a11 += x1*y1;
    }
    __syncthreads();
  }
  float* outp = att_p + (size_t)kc*256*300;
  int r0 = bm + ty*2, c0 = bn + tx*2;
  #pragma unroll
  for (int i = 0; i < 2; ++i){
    #pragma unroll
    for (int j = 0; j < 2; ++j){
      int r = r0 + i, c = c0 + j;
      if (c < 300)
        outp[(size_t)r*300 + c] = (i==0 ? (j==0?a00:a01) : (j==0?a10:a11));
    }
  }
}

__global__ __launch_bounds__(64)
void k_att_stats(const float* __restrict__ att_p, const float* __restrict__ Fbar_s,
                 const float* __restrict__ b2, const float* __restrict__ ssum_g,
                 const float* __restrict__ ssq_g,
                 float* __restrict__ att, float* __restrict__ m_g, float* __restrict__ rs_g){
  int bb = blockIdx.x, lane = threadIdx.x;
  const size_t Q = (size_t)256*300;
  float s = 0.f, q = 0.f;
  for (int j = lane; j < 300; j += 64){
    size_t i = (size_t)bb*300 + j;
    float v = (att_p[i] + att_p[Q+i]) + (att_p[2*Q+i] + att_p[3*Q+i]);
    v += b2[j] + Fbar_s[i];
    att[i] = v;
    s += v; q += v*v;
  }
  for (int o = 32; o > 0; o >>= 1){ s += __shfl_xor(s, o); q += __shfl_xor(q, o); }
  if (lane == 0){
    float m = (ssum_g[bb] + s) * (1.f/600.f);
    float var = (ssq_g[bb] + q) * (1.f/600.f) - m*m;
    m_g[bb] = m;
    rs_g[bb] = 1.f / sqrtf(var + 1e-5f);
  }
}

__global__ __launch_bounds__(256)
void k_mlp1_sk(const float* __restrict__ sgs, const float* __restrict__ att,
               const float* __restrict__ m_g, const float* __restrict__ rs_g,
               const float* __restrict__ ln2g, const float* __restrict__ ln2b,
               const float* __restrict__ aw1, float* __restrict__ g2_p){
  __shared__ float As[32][33], Bs[32][33];
  int t = threadIdx.x;
  int bm = blockIdx.x*32, bn = blockIdx.y*32, kc = blockIdx.z;
  int tx = t & 15, ty = t >> 4;
  int kbeg = kc*160, kend = (kc == 3) ? 608 : kbeg + 160;
  float a00=0.f,a01=0.f,a10=0.f,a11=0.f;
  for (int k0 = kbeg; k0 < kend; k0 += 32){
    #pragma unroll
    for (int i = 0; i < 4; ++i){
      int idx = t + i*256;
      int kk = idx & 31, m = idx >> 5;
      int kg = k0 + kk, row = bm + m;
      float t2 = 0.f;
      if (kg < 600){
        float x = (kg < 300) ? sgs[(size_t)row*300 + kg] : att[(size_t)row*300 + kg - 300];
        t2 = (x - m_g[row])*rs_g[row]*ln2g[kg] + ln2b[kg];
      }
      As[kk][m] = t2;
    }
    #pragma unroll
    for (int i = 0; i < 4; ++i){
      int idx = t + i*256;
      int n = idx & 31, kk = idx >> 5;
      int kg = k0 + kk, cg = bn + n;
      Bs[kk][n] = (kg < 600 && cg < 600) ? aw1[(size_t)kg*600 + cg] : 0.f;
    }
    __syncthreads();
    #pragma unroll
    for (int kk = 0; kk < 32; ++kk){
      float x0 = As[kk][ty*2], x1 = As[kk][ty*2+1];
      float y0 = Bs[kk][tx*2], y1 = Bs[kk][tx*2+1];
      a00 += x0*y0; a01 += x0*y1; a10 += x1*y0; a11 += x1*y1;
    }
    __syncthreads();
  }
  float* outp = g2_p + (size_t)kc*256*608;
  int r0 = bm + ty*2, c0 = bn + tx*2;
  #pragma unroll
  for (int i = 0; i < 2; ++i){
    #pragma unroll
    for (int j = 0; j < 2; ++j){
      int r = r0 + i, c = c0 + j;
      outp[(size_t)r*608 + c] = (i==0 ? (j==0?a00:a01) : (j==0?a10:a11));
    }
  }
}

__global__ __launch_bounds__(256)
void k_mlp1_red(const float* __restrict__ g2_p, const float* __restrict__ ab1,
                float* __restrict__ g2){
  int i = blockIdx.x*256 + threadIdx.x;
  if (i >= 256*608) return;
  const size_t Q = (size_t)256*608;
  int c = i % 608;
  float s = (g2_p[i] + g2_p[Q+i]) + (g2_p[2*Q+i] + g2_p[3*Q+i]);
  g2[i] = (c < 600) ? geluf(s + ab1[c]) : 0.f;
}

__global__ __launch_bounds__(256)
void k_mlp2_sk(const float* __restrict__ g2, const float* __restrict__ aw2,
               float* __restrict__ fin_p){
  __shared__ float As[32][33], Bs[32][33];
  int t = threadIdx.x;
  int bm = blockIdx.x*32, bn = blockIdx.y*32, kc = blockIdx.z;
  int tx = t & 15, ty = t >> 4;
  int kbeg = kc*160, kend = (kc == 3) ? 608 : kbeg + 160;
  float a00=0.f,a01=0.f,a10=0.f,a11=0.f;
  for (int k0 = kbeg; k0 < kend; k0 += 32){
    #pragma unroll
    for (int i = 0; i < 4; ++i){
      int idx = t + i*256;
      int kk = idx & 31, m = idx >> 5;
      As[kk][m] = g2[(size_t)(bm+m)*608 + k0 + kk];
    }
    #pragma unroll
    for (int i = 0; i < 4; ++i){
      int idx = t + i*256;
      int n = idx & 31, kk = idx >> 5;
      int kg = k0 + kk, cg = bn + n;
      Bs[kk][n] = (kg < 600 && cg < 300) ? aw2[(size_t)kg*300 + cg] : 0.f;
    }
    __syncthreads();
    #pragma unroll
    for (int kk = 0; kk < 32; ++kk){
      float x0 = As[kk][ty*2], x1 = As[kk][ty*2+1];
      float y0 = Bs[kk][tx*2], y1 = Bs[kk][tx*2+1];
      a00 += x0*y0; a01 += x0*y1; a10 += x1*y0; a11 += x1*y1;
    }
    __syncthreads();
  }
  float* outp = fin_p + (size_t)kc*256*300;
  int r0 = bm + ty*2, c0 = bn + tx*2;
  #pragma unroll
  for (int i = 0; i < 2; ++i){
    #pragma unroll
    for (int j = 0; j < 2; ++j){
      int r = r0 + i, c = c0 + j;
      if (c < 300)
        outp[(size_t)r*300 + c] = (i==0 ? (j==0?a00:a01) : (j==0?a10:a11));
    }
  }
}

__global__ __launch_bounds__(64)
void k_mlp2cos(const float* __restrict__ fin_p, const float* __restrict__ sgs,
               const float* __restrict__ ab2, float* __restrict__ out){
  int b = blockIdx.x, lane = threadIdx.x;
  const size_t Q = (size_t)256*300;
  float dot = 0.f, na = 0.f, nb = 0.f;
  for (int j = lane; j < 300; j += 64){
    size_t ia = (size_t)b*300 + j;
    size_t ib = (size_t)(128 + b)*300 + j;
    float xa = (fin_p[ia] + fin_p[Q+ia]) + (fin_p[2*Q+ia] + fin_p[3*Q+ia]);
    xa += ab2[j] + sgs[ia];
    float xb = (fin_p[ib] + fin_p[Q+ib]) + (fin_p[2*Q+ib] + fin_p[3*Q+ib]);
    xb += ab2[j] + sgs[ib];
    dot += xa*xb; na += xa*xa; nb += xb*xb;
  }
  for (int o = 32; o > 0; o >>= 1){
    dot += __shfl_xor(dot, o); na += __shfl_xor(na, o); nb += __shfl_xor(nb, o);
  }
  if (lane == 0){
    float den = fmaxf(sqrtf(na), 1e-8f) * fmaxf(sqrtf(nb), 1e-8f);
    out[b] = 5.f * dot / den;
  }
}

extern "C" void kernel_launch(void* const* d_in, const int* in_sizes, int n_in,
                              void* d_out, int out_size, void* d_ws, size_t ws_size,
                              hipStream_t stream) {
  const int* ids_a = (const int*)d_in[0];
  const void* mask_a = d_in[1];
  const int* ids_b = (const int*)d_in[2];
  const void* mask_b = d_in[3];
  const float* mu_tab     = (const float*)d_in[4];
  const float* logvar_tab = (const float*)d_in[5];
  const float* alpha_tab  = (const float*)d_in[6];
  const float* feat_tab   = (const float*)d_in[7];
  const float* log_tau    = (const float*)d_in[8];
  const float* pos_mu     = (const float*)d_in[9];
  const float* pos_alpha  = (const float*)d_in[10];
  const float* ln1g = (const float*)d_in[11];
  const float* ln1b = (const float*)d_in[12];
  const float* w1   = (const float*)d_in[13];
  const float* b1   = (const float*)d_in[14];
  const float* w2   = (const float*)d_in[15];
  const float* b2   = (const float*)d_in[16];
  const float* wq   = (const float*)d_in[17];
  const float* bq   = (const float*)d_in[18];
  const float* wk   = (const float*)d_in[19];
  const float* bk   = (const float*)d_in[20];
  const float* ln2g = (const float*)d_in[21];
  const float* ln2b = (const float*)d_in[22];
  const float* aw1  = (const float*)d_in[23];
  const float* ab1  = (const float*)d_in[24];
  const float* aw2  = (const float*)d_in[25];
  const float* ab2  = (const float*)d_in[26];
  float* out = (float*)d_out;

  char* wsb = (char*)d_ws;
  size_t off = 0;
  auto take = [&](size_t bytes) -> void* {
    void* p = wsb + off;
    off += (bytes + 255) & ~(size_t)255;
    return p;
  };

  const size_t uBytes  = (size_t)30000 * 600 * 2;   // 36.0 MB
  const size_t aBytes  = (size_t)30080 * 320 * 2;   // 19.3 MB (stays live)
  const size_t btBytes = (size_t)640 * 320 * 2;     // 0.41 MB
  const size_t muBytes = (size_t)256 * 512 * 64 * 2;// 16.8 MB (aliased post-stage1)
  const size_t need = uBytes + aBytes + btBytes + muBytes + ((size_t)8 << 20);
  if (ws_size < need) return;

  __hip_bfloat16* U = (__hip_bfloat16*)take(uBytes);
  ushort* Abf = (ushort*)take(aBytes);
  ushort* BTbf = (ushort*)take(btBytes);
  char* muRegion = (char*)take(muBytes);
  ushort* MuS = (ushort*)muRegion;
  float* hbar_p = (float*)(muRegion + 0);                 // 8*256*608*4 = 4,980,736
  float* Fbar_p = (float*)(muRegion + 4980736);           // 8*256*300*4 = 2,457,600
  float* att_g  = (float*)(muRegion + 7438336);           //   307,200
  float* g2_g   = (float*)(muRegion + 7745536);           //   622,592
  float* hbar_s = (float*)(muRegion + 8675328);           //   622,592
  float* Fbar_s = (float*)(muRegion + 9297920);           //   307,200
  float* att_p  = (float*)(muRegion + 9605120);           // 4*256*300*4 = 1,228,800
  float* g2_p   = (float*)(muRegion + 10833920);          // 4*256*608*4 = 2,490,368
  float* fin_p  = (float*)(muRegion + 13324288);          // 4*256*300*4 = 1,228,800

  float* fsum   = (float*)take(30000*4);
  float* fsq    = (float*)take(30000*4);
  float* gw_g   = (float*)take(600*4);
  float* c_g    = (float*)take(600*4);
  float* sgs_g  = (float*)take(256*300*4);
  float* ssum_g = (float*)take(256*4);
  float* ssq_g  = (float*)take(256*4);
  float* V_g    = (float*)take(256*600*4);
  float* wgt_g  = (float*)take(256*512*4);
  float* m_g    = (float*)take(256*4);
  float* rs_g   = (float*)take(256*4);
  float* cent_p = (float*)take((size_t)2048*64*4);
  float* msum_p = (float*)take(2048*4);
  float* al_g   = (float*)take((size_t)256*512*4);
  float* wsum_p = (float*)take(2048*4);
  float* sgs_p  = (float*)take((size_t)2048*304*4);

  k_pack_stats<<<7520, 256, 0, stream>>>(feat_tab, Abf, fsum, fsq);
  k_pack_b<<<(640*320 + 255)/256, 256, 0, stream>>>(w1, ln1g, BTbf);
  k_gw<<<3, 256, 0, stream>>>(w1, ln1g, ln1b, b1, gw_g, c_g);
  k_ugemm_mfma<<<dim3(235, 5), 256, 0, stream>>>(Abf, BTbf, U);
  k_mu_stage<<<2048, 256, 0, stream>>>(ids_a, mask_a, ids_b, mask_b,
                                       mu_tab, pos_mu, alpha_tab, pos_alpha,
                                       MuS, cent_p, msum_p, al_g);
  k_wrender<<<2048, 256, 0, stream>>>(ids_a, ids_b, logvar_tab, MuS, cent_p, msum_p,
                                      al_g, log_tau, Abf, wsum_p, sgs_p);
  k_stage1c<<<256, 512, 0, stream>>>(ids_a, mask_a, ids_b, mask_b,
                                     MuS, sgs_p, wsum_p,
                                     wq, bq, wk, bk,
                                     sgs_g, ssum_g, ssq_g, wgt_g);
  k_vgemm2<<<dim3(8, 19), 256, 0, stream>>>(sgs_g, w1, ln1g, V_g);
  k_hbar_fbar<<<2048, 256, 0, stream>>>(ids_a, ids_b, U, Abf, fsum, fsq,
                                        ssum_g, ssq_g, V_g, gw_g, c_g, wgt_g,
                                        hbar_p, Fbar_p);
  k_hreduce<<<608, 256, 0, stream>>>(hbar_p, Fbar_p, hbar_s, Fbar_s);
  k_att_sk<<<dim3(8, 10, 4), 256, 0, stream>>>(hbar_s, w2, att_p);
  k_att_stats<<<256, 64, 0, stream>>>(att_p, Fbar_s, b2, ssum_g, ssq_g, att_g, m_g, rs_g);
  k_mlp1_sk<<<dim3(8, 19, 4), 256, 0, stream>>>(sgs_g, att_g, m_g, rs_g, ln2g, ln2b, aw1, g2_p);
  k_mlp1_red<<<608, 256, 0, stream>>>(g2_p, ab1, g2_g);
  k_mlp2_sk<<<dim3(8, 10, 4), 256, 0, stream>>>(g2_g, aw2, fin_p);
  k_mlp2cos<<<128, 64, 0, stream>>>(fin_p, sgs_g, ab2, out);
}

// Round 15
// 262.095 us; speedup vs baseline: 1.0020x; 1.0020x over previous
//
#include <hip/hip_runtime.h>
#include <hip/hip_bf16.h>
#include <cstdint>
#include <cstddef>

#define DEV __device__ __forceinline__

// problem constants: B=128, S=512, V=30000, DS=64, DF=300, H=600, BB=256

typedef __attribute__((ext_vector_type(8))) short bf16x8;
typedef __attribute__((ext_vector_type(4))) float f32x4;

DEV float geluf(float x){ return 0.5f*x*(1.f + erff(x*0.7071067811865475f)); }
DEV float gelu_fast(float x){
  float x2 = x*x;
  float e = __builtin_amdgcn_exp2f(x * __builtin_fmaf(x2, -0.102953f, -2.302218f));
  return x * __builtin_amdgcn_rcpf(1.f + e);
}

DEV float wave_sum(float v){
  v += __shfl_xor(v, 1); v += __shfl_xor(v, 2); v += __shfl_xor(v, 4);
  v += __shfl_xor(v, 8); v += __shfl_xor(v, 16); v += __shfl_xor(v, 32);
  return v;
}
DEV float wave_max(float v){
  v = fmaxf(v, __shfl_xor(v, 1)); v = fmaxf(v, __shfl_xor(v, 2));
  v = fmaxf(v, __shfl_xor(v, 4)); v = fmaxf(v, __shfl_xor(v, 8));
  v = fmaxf(v, __shfl_xor(v, 16)); v = fmaxf(v, __shfl_xor(v, 32));
  return v;
}
// 512-thread block sum via wave shuffles + 8-slot LDS (2 barriers)
DEV float blk_sum512w(float* red8, int t, float v){
  float w = wave_sum(v);
  if ((t & 63) == 0) red8[t >> 6] = w;
  __syncthreads();
  float r = (red8[0] + red8[1]) + (red8[2] + red8[3])
          + (red8[4] + red8[5]) + (red8[6] + red8[7]);
  __syncthreads();
  return r;
}
DEV float blk_max512w(float* red8, int t, float v){
  float w = wave_max(v);
  if ((t & 63) == 0) red8[t >> 6] = w;
  __syncthreads();
  float r = fmaxf(fmaxf(fmaxf(red8[0], red8[1]), fmaxf(red8[2], red8[3])),
                  fmaxf(fmaxf(red8[4], red8[5]), fmaxf(red8[6], red8[7])));
  __syncthreads();
  return r;
}
DEV float blk_sum256(float* red, int t, float v){
  red[t] = v; __syncthreads();
  for (int o = 128; o > 0; o >>= 1){ if (t < o) red[t] += red[t+o]; __syncthreads(); }
  float r = red[0]; __syncthreads(); return r;
}

DEV ushort f2bf(float v){ __hip_bfloat16 h = __float2bfloat16(v); return *(ushort*)&h; }
DEV float bf2f(ushort u){ __hip_bfloat16 h; *(ushort*)&h = u; return __bfloat162float(h); }

// ---- mask dtype classifier ----
DEV int mask_mode(const unsigned char* m){
  bool big = false, off123 = false, off0one = false;
  #pragma unroll
  for (int i = 0; i < 16; ++i){
    unsigned char c = m[i];
    if (c > 1) big = true;
    if ((i & 3) != 0 && c != 0) off123 = true;
    if ((i & 3) == 0 && c == 1) off0one = true;
  }
  if (big) return 2;
  if (!off123 && off0one) return 1;
  return 0;
}
DEV float mask_read(const void* m, int idx, int mode){
  if (mode == 1) return ((const int*)m)[idx] ? 1.f : 0.f;
  if (mode == 2) return ((const unsigned short*)m)[idx] ? 1.f : 0.f;
  return ((const unsigned char*)m)[idx] ? 1.f : 0.f;
}

// ---------------- fused: pack A + per-vocab stats ----------------
__global__ __launch_bounds__(256)
void k_pack_stats(const float* __restrict__ feat, ushort* __restrict__ A,
                  float* __restrict__ fsum, float* __restrict__ fsq){
  int v = blockIdx.x*4 + (threadIdx.x >> 6);
  int ln = threadIdx.x & 63;
  if (v >= 30080) return;
  float vals[8] = {0.f,0.f,0.f,0.f,0.f,0.f,0.f,0.f};
  if (v < 30000 && ln < 38){
    const float* fr = &feat[(size_t)v*300];
    if (ln < 37){
      float4 a = *(const float4*)&fr[ln*8];
      float4 b = *(const float4*)&fr[ln*8 + 4];
      vals[0]=a.x; vals[1]=a.y; vals[2]=a.z; vals[3]=a.w;
      vals[4]=b.x; vals[5]=b.y; vals[6]=b.z; vals[7]=b.w;
    } else {
      float4 a = *(const float4*)&fr[296];
      vals[0]=a.x; vals[1]=a.y; vals[2]=a.z; vals[3]=a.w;
    }
  }
  if (ln < 40){
    union { ushort u[8]; bf16x8 v8; } pk;
    #pragma unroll
    for (int i = 0; i < 8; ++i) pk.u[i] = f2bf(vals[i]);
    *(bf16x8*)&A[(size_t)v*320 + ln*8] = pk.v8;
  }
  float s = 0.f, q = 0.f;
  #pragma unroll
  for (int i = 0; i < 8; ++i){ s += vals[i]; q += vals[i]*vals[i]; }
  for (int o = 32; o > 0; o >>= 1){ s += __shfl_xor(s, o); q += __shfl_xor(q, o); }
  if (ln == 0 && v < 30000){ fsum[v] = s; fsq[v] = q; }
}

// ---------------- fused gw: gw_g[j]=sum_i g[i]*w1[i,j]; c_g[j]=sum_i bln[i]*w1[i,j] + b1[j] ----------------
__global__ __launch_bounds__(256)
void k_gw(const float* __restrict__ w1, const float* __restrict__ g,
          const float* __restrict__ bln, const float* __restrict__ b1,
          float* __restrict__ gw_g, float* __restrict__ c_g){
  int j = blockIdx.x*256 + threadIdx.x;
  if (j >= 600) return;
  float a = 0.f, c = 0.f;
  for (int i = 0; i < 600; ++i){
    float w = w1[(size_t)i*600 + j];
    a += g[i]*w; c += bln[i]*w;
  }
  gw_g[j] = a; c_g[j] = c + b1[j];
}

// ---------------- pack B^T ----------------
__global__ __launch_bounds__(256)
void k_pack_b(const float* __restrict__ w1, const float* __restrict__ g, ushort* __restrict__ BT){
  int id = blockIdx.x*256 + threadIdx.x;
  if (id >= 640*320) return;
  int n = id % 640, k = id / 640;
  float val = (k < 300 && n < 600) ? g[k]*w1[k*600 + n] : 0.f;
  BT[(size_t)n*320 + k] = f2bf(val);
}

// ---------------- P1: U GEMM (MFMA) ----------------
__global__ __launch_bounds__(256)
void k_ugemm_mfma(const ushort* __restrict__ A, const ushort* __restrict__ BT,
                  __hip_bfloat16* __restrict__ U){
  __shared__ ushort As[128][40];
  __shared__ ushort Bs[128][40];
  int tid = threadIdx.x;
  int bm = blockIdx.x * 128, bn = blockIdx.y * 128;
  int wid = tid >> 6, lane = tid & 63;
  int wr = wid >> 1, wc = wid & 1;
  int lr = lane & 15, lk = lane >> 4;
  f32x4 acc[4][4] = {};
  for (int k0 = 0; k0 < 320; k0 += 32){
    #pragma unroll
    for (int j = 0; j < 2; ++j){
      int idx = tid + 256*j;
      int row = idx >> 2, ko = (idx & 3)*8;
      *(bf16x8*)&As[row][ko] = *(const bf16x8*)&A[(size_t)(bm+row)*320 + k0 + ko];
      *(bf16x8*)&Bs[row][ko] = *(const bf16x8*)&BT[(size_t)(bn+row)*320 + k0 + ko];
    }
    __syncthreads();
    bf16x8 af[4], bfr[4];
    #pragma unroll
    for (int f = 0; f < 4; ++f){
      af[f]  = *(const bf16x8*)&As[wr*64 + f*16 + lr][lk*8];
      bfr[f] = *(const bf16x8*)&Bs[wc*64 + f*16 + lr][lk*8];
    }
    #pragma unroll
    for (int i = 0; i < 4; ++i)
      #pragma unroll
      for (int j = 0; j < 4; ++j)
        acc[i][j] = __builtin_amdgcn_mfma_f32_16x16x32_bf16(af[i], bfr[j], acc[i][j], 0, 0, 0);
    __syncthreads();
  }
  #pragma unroll
  for (int i = 0; i < 4; ++i){
    #pragma unroll
    for (int j = 0; j < 4; ++j){
      #pragma unroll
      for (int r = 0; r < 4; ++r){
        int row = bm + wr*64 + i*16 + lk*4 + r;
        int col = bn + wc*64 + j*16 + lr;
        if (row < 30000 && col < 600)
          U[(size_t)row*600 + col] = __float2bfloat16(acc[i][j][r]);
      }
    }
  }
}

// ---------------- S1a: mu gather+stage ----------------
__global__ __launch_bounds__(256)
void k_mu_stage(const int* __restrict__ ids_a, const void* __restrict__ mask_a,
                const int* __restrict__ ids_b, const void* __restrict__ mask_b,
                const float* __restrict__ mu_tab, const float* __restrict__ pos_mu,
                const float* __restrict__ alpha_tab, const float* __restrict__ pos_alpha,
                ushort* __restrict__ MuS, float* __restrict__ cent_p,
                float* __restrict__ msum_p, float* __restrict__ al_g){
  int blk = blockIdx.x;
  int bb = blk >> 3, qr = blk & 7;
  int b = bb & 127;
  const int* ids = (bb < 128) ? ids_a : ids_b;
  const void* msk = (bb < 128) ? mask_a : mask_b;
  int t = threadIdx.x;
  int grp = t >> 4, sub = t & 15;
  __shared__ int mmode_s;
  __shared__ float gpart[16][64];
  __shared__ float mf_s[64];
  __shared__ float red[256];
  if (t == 0) mmode_s = mask_mode((const unsigned char*)msk);
  __syncthreads();
  int mmode = mmode_s;
  float cp0=0.f, cp1=0.f, cp2=0.f, cp3=0.f;
  #pragma unroll
  for (int k = 0; k < 4; ++k){
    int sl = grp*4 + k;
    int s  = qr*64 + sl;
    int id = ids[b*512 + s];
    float mf = mask_read(msk, b*512 + s, mmode);
    float4 m4 = *(const float4*)&mu_tab[(size_t)id*64 + sub*4];
    float4 p4 = *(const float4*)&pos_mu[s*64 + sub*4];
    float v0 = m4.x+p4.x, v1 = m4.y+p4.y, v2 = m4.z+p4.z, v3 = m4.w+p4.w;
    ushort4 st; st.x = f2bf(v0); st.y = f2bf(v1); st.z = f2bf(v2); st.w = f2bf(v3);
    *(ushort4*)&MuS[((size_t)bb*512 + s)*64 + sub*4] = st;
    cp0 += mf*v0; cp1 += mf*v1; cp2 += mf*v2; cp3 += mf*v3;
    if (sub == 0){
      mf_s[sl] = mf;
      float pa = pos_alpha[s];
      float sg = __builtin_amdgcn_rcpf(1.f + __builtin_amdgcn_exp2f(-1.44269504f*pa));
      al_g[bb*512 + s] = alpha_tab[id] * sg * mf;
    }
  }
  gpart[grp][sub*4+0] = cp0; gpart[grp][sub*4+1] = cp1;
  gpart[grp][sub*4+2] = cp2; gpart[grp][sub*4+3] = cp3;
  __syncthreads();
  if (t < 64){
    float c = 0.f;
    #pragma unroll
    for (int g = 0; g < 16; ++g) c += gpart[g][t];
    cent_p[(size_t)blk*64 + t] = c;
  }
  float ms = blk_sum256(red, t, (t < 64) ? mf_s[t] : 0.f);
  if (t == 0) msum_p[blk] = ms;
}

// ---------------- S1c: cent reduce (fused) + w = alpha*K + render partials ----------------
__global__ __launch_bounds__(256)
void k_wrender(const int* __restrict__ ids_a, const int* __restrict__ ids_b,
               const float* __restrict__ logvar_tab, const ushort* __restrict__ MuS,
               const float* __restrict__ cent_p, const float* __restrict__ msum_p,
               const float* __restrict__ al_g,
               const float* __restrict__ log_tau, const ushort* __restrict__ Abf,
               float* __restrict__ wsum_p, float* __restrict__ sgs_p){
  int blk = blockIdx.x;
  int bb = blk >> 3, qr = blk & 7;
  int b = bb & 127;
  const int* ids = (bb < 128) ? ids_a : ids_b;
  int t = threadIdx.x;
  int grp = t >> 4, sub = t & 15;
  __shared__ float cent_s[64];
  __shared__ float wl[64];
  __shared__ int   idl[64];
  __shared__ float pacc[4][304];
  __shared__ float red[256];
  // fused centroid reduce (redundant per block, trivial)
  if (t < 64){
    float c = 0.f, ms = 0.f;
    #pragma unroll
    for (int q = 0; q < 8; ++q){
      c  += cent_p[(size_t)(bb*8+q)*64 + t];
      ms += msum_p[bb*8+q];
    }
    cent_s[t] = c / fmaxf(ms, 1.f);
  }
  __syncthreads();
  float itau = __builtin_amdgcn_exp2f(-1.44269504f*log_tau[0]);
  float c0 = cent_s[sub*4+0], c1 = cent_s[sub*4+1];
  float c2 = cent_s[sub*4+2], c3 = cent_s[sub*4+3];
  #pragma unroll
  for (int k = 0; k < 4; ++k){
    int sl = grp*4 + k, s = qr*64 + sl;
    int id = ids[b*512 + s];
    float4 lv = *(const float4*)&logvar_tab[(size_t)id*64 + sub*4];
    float iv0 = __builtin_amdgcn_exp2f(-1.44269504f*lv.x);
    float iv1 = __builtin_amdgcn_exp2f(-1.44269504f*lv.y);
    float iv2 = __builtin_amdgcn_exp2f(-1.44269504f*lv.z);
    float iv3 = __builtin_amdgcn_exp2f(-1.44269504f*lv.w);
    ushort4 mu = *(const ushort4*)&MuS[((size_t)bb*512 + s)*64 + sub*4];
    float d0 = bf2f(mu.x)-c0, d1 = bf2f(mu.y)-c1, d2v = bf2f(mu.z)-c2, d3 = bf2f(mu.w)-c3;
    float val = d0*d0*iv0 + d1*d1*iv1 + d2v*d2v*iv2 + d3*d3*iv3;
    val += __shfl_xor(val, 1); val += __shfl_xor(val, 2);
    val += __shfl_xor(val, 4); val += __shfl_xor(val, 8);
    if (sub == 0){
      idl[sl] = id;
      float K = __builtin_amdgcn_exp2f(-0.72134752f * val * itau);
      wl[sl] = al_g[bb*512 + s] * K;
    }
  }
  __syncthreads();
  float ws = blk_sum256(red, t, (t < 64) ? wl[t] : 0.f);
  if (t == 0) wsum_p[blk] = ws;
  int wv = t >> 6, ln = t & 63;
  if (ln < 38){
    float a[8] = {};
    for (int k = 0; k < 16; ++k){
      int sl = (wv << 4) | k;
      float w = wl[sl];
      bf16x8 f8 = *(const bf16x8*)&Abf[(size_t)idl[sl]*320 + ln*8];
      #pragma unroll
      for (int r = 0; r < 8; ++r) a[r] += w * bf2f((ushort)f8[r]);
    }
    #pragma unroll
    for (int r = 0; r < 8; ++r) pacc[wv][ln*8 + r] = a[r];
  }
  __syncthreads();
  for (int j = t; j < 300; j += 256)
    sgs_p[(size_t)blk*304 + j] = pacc[0][j] + pacc[1][j] + pacc[2][j] + pacc[3][j];
}

// ---------------- S1d: sgs reduce, query, scores, softmax (wave reductions) ----------------
__global__ __launch_bounds__(512)
void k_stage1c(const int* __restrict__ ids_a, const void* __restrict__ mask_a,
               const int* __restrict__ ids_b, const void* __restrict__ mask_b,
               const ushort* __restrict__ MuS, const float* __restrict__ sgs_p,
               const float* __restrict__ wsum_p,
               const float* __restrict__ wq, const float* __restrict__ bq,
               const float* __restrict__ wk, const float* __restrict__ bk,
               float* __restrict__ sgs_g, float* __restrict__ ssum_g, float* __restrict__ ssq_g,
               float* __restrict__ wgt_g)
{
  int bb = blockIdx.x;
  const void* msk = (bb < 128) ? mask_a : mask_b;
  int b = bb & 127;
  int t = threadIdx.x;
  __shared__ float mf_l[512], w_l[512];
  __shared__ float red8[8], red8b[8];
  __shared__ float q_l[64], qk_l[64];
  __shared__ float sgs_l[304];
  __shared__ float bkq_s;
  __shared__ int mmode;
  if (t == 0) mmode = mask_mode((const unsigned char*)msk);
  __syncthreads();
  mf_l[t] = mask_read(msk, b*512 + t, mmode);

  float wsum = 0.f;
  #pragma unroll
  for (int q = 0; q < 8; ++q) wsum += wsum_p[bb*8 + q];
  wsum = fmaxf(wsum, 1e-8f);
  if (t < 300){
    float sa = 0.f;
    #pragma unroll
    for (int q = 0; q < 8; ++q) sa += sgs_p[(size_t)(bb*8+q)*304 + t];
    float sv = sa / wsum;
    sgs_l[t] = sv;
    sgs_g[bb*300 + t] = sv;
  }
  __syncthreads();
  {
    float v1 = (t < 300) ? sgs_l[t] : 0.f;
    float s1 = wave_sum(v1), s2 = wave_sum(v1*v1);
    if ((t & 63) == 0){ red8[t >> 6] = s1; red8b[t >> 6] = s2; }
    __syncthreads();
    if (t == 0){
      float ssum = (red8[0]+red8[1])+(red8[2]+red8[3])+(red8[4]+red8[5])+(red8[6]+red8[7]);
      float ssq  = (red8b[0]+red8b[1])+(red8b[2]+red8b[3])+(red8b[4]+red8b[5])+(red8b[6]+red8b[7]);
      ssum_g[bb] = ssum; ssq_g[bb] = ssq;
    }
  }

  if (t < 64){
    float q = bq[t];
    for (int i = 0; i < 300; ++i) q += sgs_l[i]*wq[i*64 + t];
    q_l[t] = q;
  }
  __syncthreads();
  if (t < 64){
    float a = 0.f;
    for (int j = 0; j < 64; ++j) a += wk[t*64 + j]*q_l[j];
    qk_l[t] = a;
  }
  if (t == 0){
    float s = 0.f;
    for (int j = 0; j < 64; ++j) s += bk[j]*q_l[j];
    bkq_s = s;
  }
  __syncthreads();

  int grp = t >> 4, sub = t & 15;
  {
    float q0 = qk_l[sub*4+0], q1 = qk_l[sub*4+1], q2 = qk_l[sub*4+2], q3 = qk_l[sub*4+3];
    for (int k = 0; k < 16; ++k){
      int s = (grp << 4) | k;
      ushort4 mu = *(const ushort4*)&MuS[((size_t)bb*512 + s)*64 + sub*4];
      float val = bf2f(mu.x)*q0 + bf2f(mu.y)*q1 + bf2f(mu.z)*q2 + bf2f(mu.w)*q3;
      val += __shfl_xor(val, 1); val += __shfl_xor(val, 2);
      val += __shfl_xor(val, 4); val += __shfl_xor(val, 8);
      if (sub == 0){
        float sv = (val + bkq_s) * 0.125f;
        w_l[s] = (mf_l[s] != 0.f) ? sv : -1e30f;
      }
    }
  }
  __syncthreads();

  float mx = blk_max512w(red8, t, w_l[t]);
  float ex = __expf(w_l[t] - mx);
  float Z  = blk_sum512w(red8, t, ex);
  wgt_g[bb*512 + t] = ex / Z;
}

// ---------------- k_vgemm2 ----------------
__global__ __launch_bounds__(256)
void k_vgemm2(const float* __restrict__ sgs, const float* __restrict__ w1,
              const float* __restrict__ ln1g, float* __restrict__ V_g){
  __shared__ float As[32][33], Bs[32][33];
  int t = threadIdx.x;
  int bm = blockIdx.x*32, bn = blockIdx.y*32;
  int tx = t & 15, ty = t >> 4;
  float a00=0.f,a01=0.f,a10=0.f,a11=0.f;
  for (int k0 = 0; k0 < 300; k0 += 32){
    #pragma unroll
    for (int i = 0; i < 4; ++i){
      int idx = t + i*256;
      int kk = idx & 31, m = idx >> 5;
      int kg = k0 + kk;
      As[kk][m] = (kg < 300) ? sgs[(size_t)(bm+m)*300 + kg] : 0.f;
    }
    #pragma unroll
    for (int i = 0; i < 4; ++i){
      int idx = t + i*256;
      int n = idx & 31, kk = idx >> 5;
      int kg = k0 + kk, cg = bn + n;
      Bs[kk][n] = (kg < 300 && cg < 600) ? ln1g[300 + kg]*w1[(size_t)(300 + kg)*600 + cg] : 0.f;
    }
    __syncthreads();
    #pragma unroll
    for (int kk = 0; kk < 32; ++kk){
      float x0 = As[kk][ty*2], x1 = As[kk][ty*2+1];
      float y0 = Bs[kk][tx*2], y1 = Bs[kk][tx*2+1];
      a00 += x0*y0; a01 += x0*y1; a10 += x1*y0; a11 += x1*y1;
    }
    __syncthreads();
  }
  int r0 = bm + ty*2, c0 = bn + tx*2;
  #pragma unroll
  for (int i = 0; i < 2; ++i){
    #pragma unroll
    for (int j = 0; j < 2; ++j){
      int r = r0 + i, c = c0 + j;
      if (c < 600) V_g[(size_t)r*600 + c] = (i==0 ? (j==0?a00:a01) : (j==0?a10:a11));
    }
  }
}

// ---------------- K2: hbar + Fbar eighth-split (balanced tail) ----------------
__global__ __launch_bounds__(256)
void k_hbar_fbar(const int* __restrict__ ids_a, const int* __restrict__ ids_b,
                 const __hip_bfloat16* __restrict__ U, const ushort* __restrict__ Abf,
                 const float* __restrict__ fsum, const float* __restrict__ fsq,
                 const float* __restrict__ ssum_g, const float* __restrict__ ssq_g,
                 const float* __restrict__ V_g, const float* __restrict__ gw_g,
                 const float* __restrict__ c_g, const float* __restrict__ wgt_g,
                 float* __restrict__ hbar_p, float* __restrict__ Fbar_p)
{
  int blk = blockIdx.x;
  int bb = blk >> 3, qr = blk & 7;
  int b = bb & 127;
  const int* ids = (bb < 128) ? ids_a : ids_b;
  int t = threadIdx.x;
  __shared__ int id_l[64];
  __shared__ float m_l[64], rs_l[64], wg_l[64];
  __shared__ float hp[4][600];
  __shared__ float fp[4][304];
  float ss = ssum_g[bb], sq = ssq_g[bb];
  if (t < 64){
    int s = qr*64 + t;
    int id = ids[b*512 + s];
    id_l[t] = id;
    float m = (fsum[id] + ss) * (1.f/600.f);
    float var = (fsq[id] + sq) * (1.f/600.f) - m*m;
    m_l[t] = m;
    rs_l[t] = 1.f / sqrtf(var + 1e-5f);
    wg_l[t] = wgt_g[bb*512 + s];
  }
  __syncthreads();

  int wv = t >> 6, ln = t & 63;
  float Vp[8], gwp[8], cp[8];
  #pragma unroll
  for (int r = 0; r < 8; ++r){
    int j = ln*8 + r;
    Vp[r] = V_g[bb*600 + j]; gwp[r] = gw_g[j]; cp[r] = c_g[j];
  }
  float Vs[4] = {}, gws[4] = {}, cs[4] = {};
  if (ln < 22){
    #pragma unroll
    for (int r = 0; r < 4; ++r){
      int j = 512 + ln*4 + r;
      Vs[r] = V_g[bb*600 + j]; gws[r] = gw_g[j]; cs[r] = c_g[j];
    }
  }
  float h1[8] = {}, h2[4] = {}, fa[8] = {};

  for (int k = 0; k < 16; ++k){
    int s = (wv << 4) | k;
    int id = id_l[s];
    float w = wg_l[s], m = m_l[s], rs = rs_l[s];
    const __hip_bfloat16* ur = &U[(size_t)id*600];
    bf16x8 u8 = *(const bf16x8*)&ur[ln*8];
    #pragma unroll
    for (int r = 0; r < 8; ++r){
      float u = bf2f((ushort)u8[r]);
      float a = (u + Vp[r] - m*gwp[r])*rs + cp[r];
      h1[r] += w*gelu_fast(a);
    }
    if (ln < 22){
      ushort4 u4 = *(const ushort4*)&ur[512 + ln*4];
      float uu[4] = { bf2f(u4.x), bf2f(u4.y), bf2f(u4.z), bf2f(u4.w) };
      #pragma unroll
      for (int r = 0; r < 4; ++r){
        float a = (uu[r] + Vs[r] - m*gws[r])*rs + cs[r];
        h2[r] += w*gelu_fast(a);
      }
    }
    if (ln < 38){
      bf16x8 f8 = *(const bf16x8*)&Abf[(size_t)id*320 + ln*8];
      #pragma unroll
      for (int r = 0; r < 8; ++r) fa[r] += w * bf2f((ushort)f8[r]);
    }
  }
  #pragma unroll
  for (int r = 0; r < 8; ++r) hp[wv][ln*8 + r] = h1[r];
  if (ln < 22){
    #pragma unroll
    for (int r = 0; r < 4; ++r) hp[wv][512 + ln*4 + r] = h2[r];
  }
  if (ln < 38){
    #pragma unroll
    for (int r = 0; r < 8; ++r) fp[wv][ln*8 + r] = fa[r];
  }
  __syncthreads();
  size_t hbase = ((size_t)qr*256 + bb)*608;
  for (int j = t; j < 600; j += 256){
    hbar_p[hbase + j] = hp[0][j] + hp[1][j] + hp[2][j] + hp[3][j];
  }
  if (t < 8) hbar_p[hbase + 600 + t] = 0.f;
  size_t fbase = ((size_t)qr*256 + bb)*300;
  for (int j = t; j < 300; j += 256){
    Fbar_p[fbase + j] = fp[0][j] + fp[1][j] + fp[2][j] + fp[3][j];
  }
}

// ---------------- k_hreduce ----------------
__global__ __launch_bounds__(256)
void k_hreduce(const float* __restrict__ hbar_p, const float* __restrict__ Fbar_p,
               float* __restrict__ hbar_s, float* __restrict__ Fbar_s){
  int i = blockIdx.x*256 + threadIdx.x;
  const size_t Q  = (size_t)256*608;
  const size_t QF = (size_t)256*300;
  if (i < 256*608){
    float s0 = hbar_p[i]       + hbar_p[Q + i];
    float s1 = hbar_p[2*Q + i] + hbar_p[3*Q + i];
    float s2 = hbar_p[4*Q + i] + hbar_p[5*Q + i];
    float s3 = hbar_p[6*Q + i] + hbar_p[7*Q + i];
    hbar_s[i] = (s0 + s1) + (s2 + s3);
  }
  if (i < 256*300){
    float s0 = Fbar_p[i]        + Fbar_p[QF + i];
    float s1 = Fbar_p[2*QF + i] + Fbar_p[3*QF + i];
    float s2 = Fbar_p[4*QF + i] + Fbar_p[5*QF + i];
    float s3 = Fbar_p[6*QF + i] + Fbar_p[7*QF + i];
    Fbar_s[i] = (s0 + s1) + (s2 + s3);
  }
}

// ============ final chain: split-K tiled fp32 GEMMs ============

__global__ __launch_bounds__(256)
void k_att_sk(const float* __restrict__ hbar_s, const float* __restrict__ w2,
              float* __restrict__ att_p){
  __shared__ float As[32][33], Bs[32][33];
  int t = threadIdx.x;
  int bm = blockIdx.x*32, bn = blockIdx.y*32, kc = blockIdx.z;
  int tx = t & 15, ty = t >> 4;
  int kbeg = kc*160, kend = (kc == 3) ? 608 : kbeg + 160;
  float a00=0.f,a01=0.f,a10=0.f,a11=0.f;
  for (int k0 = kbeg; k0 < kend; k0 += 32){
    #pragma unroll
    for (int i = 0; i < 4; ++i){
      int idx = t + i*256;
      int kk = idx & 31, m = idx >> 5;
      As[kk][m] = hbar_s[(size_t)(bm+m)*608 + k0 + kk];
    }
    #pragma unroll
    for (int i = 0; i < 4; ++i){
      int idx = t + i*256;
      int n = idx & 31, kk = idx >> 5;
      int kg = k0 + kk, cg = bn + n;
      Bs[kk][n] = (kg < 600 && cg < 300) ? w2[(size_t)kg*300 + cg] : 0.f;
    }
    __syncthreads();
    #pragma unroll
    for (int kk = 0; kk < 32; ++kk){
      float x0 = As[kk][ty*2], x1 = As[kk][ty*2+1];
      float y0 = Bs[kk][tx*2], y1 = Bs[kk][tx*2+1];
      a00 += x0*y0; a01 += x0*y1; a10 += x1*y0; a11 += x1*y1;
    }
    __syncthreads();
  }
  float* outp = att_p + (size_t)kc*256*300;
  int r0 = bm + ty*2, c0 = bn + tx*2;
  #pragma unroll
  for (int i = 0; i < 2; ++i){
    #pragma unroll
    for (int j = 0; j < 2; ++j){
      int r = r0 + i, c = c0 + j;
      if (c < 300)
        outp[(size_t)r*300 + c] = (i==0 ? (j==0?a00:a01) : (j==0?a10:a11));
    }
  }
}

__global__ __launch_bounds__(64)
void k_att_stats(const float* __restrict__ att_p, const float* __restrict__ Fbar_s,
                 const float* __restrict__ b2, const float* __restrict__ ssum_g,
                 const float* __restrict__ ssq_g,
                 float* __restrict__ att, float* __restrict__ m_g, float* __restrict__ rs_g){
  int bb = blockIdx.x, lane = threadIdx.x;
  const size_t Q = (size_t)256*300;
  float s = 0.f, q = 0.f;
  for (int j = lane; j < 300; j += 64){
    size_t i = (size_t)bb*300 + j;
    float v = (att_p[i] + att_p[Q+i]) + (att_p[2*Q+i] + att_p[3*Q+i]);
    v += b2[j] + Fbar_s[i];
    att[i] = v;
    s += v; q += v*v;
  }
  for (int o = 32; o > 0; o >>= 1){ s += __shfl_xor(s, o); q += __shfl_xor(q, o); }
  if (lane == 0){
    float m = (ssum_g[bb] + s) * (1.f/600.f);
    float var = (ssq_g[bb] + q) * (1.f/600.f) - m*m;
    m_g[bb] = m;
    rs_g[bb] = 1.f / sqrtf(var + 1e-5f);
  }
}

__global__ __launch_bounds__(256)
void k_mlp1_sk(const float* __restrict__ sgs, const float* __restrict__ att,
               const float* __restrict__ m_g, const float* __restrict__ rs_g,
               const float* __restrict__ ln2g, const float* __restrict__ ln2b,
               const float* __restrict__ aw1, float* __restrict__ g2_p){
  __shared__ float As[32][33], Bs[32][33];
  int t = threadIdx.x;
  int bm = blockIdx.x*32, bn = blockIdx.y*32, kc = blockIdx.z;
  int tx = t & 15, ty = t >> 4;
  int kbeg = kc*160, kend = (kc == 3) ? 608 : kbeg + 160;
  float a00=0.f,a01=0.f,a10=0.f,a11=0.f;
  for (int k0 = kbeg; k0 < kend; k0 += 32){
    #pragma unroll
    for (int i = 0; i < 4; ++i){
      int idx = t + i*256;
      int kk = idx & 31, m = idx >> 5;
      int kg = k0 + kk, row = bm + m;
      float t2 = 0.f;
      if (kg < 600){
        float x = (kg < 300) ? sgs[(size_t)row*300 + kg] : att[(size_t)row*300 + kg - 300];
        t2 = (x - m_g[row])*rs_g[row]*ln2g[kg] + ln2b[kg];
      }
      As[kk][m] = t2;
    }
    #pragma unroll
    for (int i = 0; i < 4; ++i){
      int idx = t + i*256;
      int n = idx & 31, kk = idx >> 5;
      int kg = k0 + kk, cg = bn + n;
      Bs[kk][n] = (kg < 600 && cg < 600) ? aw1[(size_t)kg*600 + cg] : 0.f;
    }
    __syncthreads();
    #pragma unroll
    for (int kk = 0; kk < 32; ++kk){
      float x0 = As[kk][ty*2], x1 = As[kk][ty*2+1];
      float y0 = Bs[kk][tx*2], y1 = Bs[kk][tx*2+1];
      a00 += x0*y0; a01 += x0*y1; a10 += x1*y0; a11 += x1*y1;
    }
    __syncthreads();
  }
  float* outp = g2_p + (size_t)kc*256*608;
  int r0 = bm + ty*2, c0 = bn + tx*2;
  #pragma unroll
  for (int i = 0; i < 2; ++i){
    #pragma unroll
    for (int j = 0; j < 2; ++j){
      int r = r0 + i, c = c0 + j;
      outp[(size_t)r*608 + c] = (i==0 ? (j==0?a00:a01) : (j==0?a10:a11));
    }
  }
}

__global__ __launch_bounds__(256)
void k_mlp1_red(const float* __restrict__ g2_p, const float* __restrict__ ab1,
                float* __restrict__ g2){
  int i = blockIdx.x*256 + threadIdx.x;
  if (i >= 256*608) return;
  const size_t Q = (size_t)256*608;
  int c = i % 608;
  float s = (g2_p[i] + g2_p[Q+i]) + (g2_p[2*Q+i] + g2_p[3*Q+i]);
  g2[i] = (c < 600) ? geluf(s + ab1[c]) : 0.f;
}

__global__ __launch_bounds__(256)
void k_mlp2_sk(const float* __restrict__ g2, const float* __restrict__ aw2,
               float* __restrict__ fin_p){
  __shared__ float As[32][33], Bs[32][33];
  int t = threadIdx.x;
  int bm = blockIdx.x*32, bn = blockIdx.y*32, kc = blockIdx.z;
  int tx = t & 15, ty = t >> 4;
  int kbeg = kc*160, kend = (kc == 3) ? 608 : kbeg + 160;
  float a00=0.f,a01=0.f,a10=0.f,a11=0.f;
  for (int k0 = kbeg; k0 < kend; k0 += 32){
    #pragma unroll
    for (int i = 0; i < 4; ++i){
      int idx = t + i*256;
      int kk = idx & 31, m = idx >> 5;
      As[kk][m] = g2[(size_t)(bm+m)*608 + k0 + kk];
    }
    #pragma unroll
    for (int i = 0; i < 4; ++i){
      int idx = t + i*256;
      int n = idx & 31, kk = idx >> 5;
      int kg = k0 + kk, cg = bn + n;
      Bs[kk][n] = (kg < 600 && cg < 300) ? aw2[(size_t)kg*300 + cg] : 0.f;
    }
    __syncthreads();
    #pragma unroll
    for (int kk = 0; kk < 32; ++kk){
      float x0 = As[kk][ty*2], x1 = As[kk][ty*2+1];
      float y0 = Bs[kk][tx*2], y1 = Bs[kk][tx*2+1];
      a00 += x0*y0; a01 += x0*y1; a10 += x1*y0; a11 += x1*y1;
    }
    __syncthreads();
  }
  float* outp = fin_p + (size_t)kc*256*300;
  int r0 = bm + ty*2, c0 = bn + tx*2;
  #pragma unroll
  for (int i = 0; i < 2; ++i){
    #pragma unroll
    for (int j = 0; j < 2; ++j){
      int r = r0 + i, c = c0 + j;
      if (c < 300)
        outp[(size_t)r*300 + c] = (i==0 ? (j==0?a00:a01) : (j==0?a10:a11));
    }
  }
}

__global__ __launch_bounds__(64)
void k_mlp2cos(const float* __restrict__ fin_p, const float* __restrict__ sgs,
               const float* __restrict__ ab2, float* __restrict__ out){
  int b = blockIdx.x, lane = threadIdx.x;
  const size_t Q = (size_t)256*300;
  float dot = 0.f, na = 0.f, nb = 0.f;
  for (int j = lane; j < 300; j += 64){
    size_t ia = (size_t)b*300 + j;
    size_t ib = (size_t)(128 + b)*300 + j;
    float xa = (fin_p[ia] + fin_p[Q+ia]) + (fin_p[2*Q+ia] + fin_p[3*Q+ia]);
    xa += ab2[j] + sgs[ia];
    float xb = (fin_p[ib] + fin_p[Q+ib]) + (fin_p[2*Q+ib] + fin_p[3*Q+ib]);
    xb += ab2[j] + sgs[ib];
    dot += xa*xb; na += xa*xa; nb += xb*xb;
  }
  for (int o = 32; o > 0; o >>= 1){
    dot += __shfl_xor(dot, o); na += __shfl_xor(na, o); nb += __shfl_xor(nb, o);
  }
  if (lane == 0){
    float den = fmaxf(sqrtf(na), 1e-8f) * fmaxf(sqrtf(nb), 1e-8f);
    out[b] = 5.f * dot / den;
  }
}

extern "C" void kernel_launch(void* const* d_in, const int* in_sizes, int n_in,
                              void* d_out, int out_size, void* d_ws, size_t ws_size,
                              hipStream_t stream) {
  const int* ids_a = (const int*)d_in[0];
  const void* mask_a = d_in[1];
  const int* ids_b = (const int*)d_in[2];
  const void* mask_b = d_in[3];
  const float* mu_tab     = (const float*)d_in[4];
  const float* logvar_tab = (const float*)d_in[5];
  const float* alpha_tab  = (const float*)d_in[6];
  const float* feat_tab   = (const float*)d_in[7];
  const float* log_tau    = (const float*)d_in[8];
  const float* pos_mu     = (const float*)d_in[9];
  const float* pos_alpha  = (const float*)d_in[10];
  const float* ln1g = (const float*)d_in[11];
  const float* ln1b = (const float*)d_in[12];
  const float* w1   = (const float*)d_in[13];
  const float* b1   = (const float*)d_in[14];
  const float* w2   = (const float*)d_in[15];
  const float* b2   = (const float*)d_in[16];
  const float* wq   = (const float*)d_in[17];
  const float* bq   = (const float*)d_in[18];
  const float* wk   = (const float*)d_in[19];
  const float* bk   = (const float*)d_in[20];
  const float* ln2g = (const float*)d_in[21];
  const float* ln2b = (const float*)d_in[22];
  const float* aw1  = (const float*)d_in[23];
  const float* ab1  = (const float*)d_in[24];
  const float* aw2  = (const float*)d_in[25];
  const float* ab2  = (const float*)d_in[26];
  float* out = (float*)d_out;

  char* wsb = (char*)d_ws;
  size_t off = 0;
  auto take = [&](size_t bytes) -> void* {
    void* p = wsb + off;
    off += (bytes + 255) & ~(size_t)255;
    return p;
  };

  const size_t uBytes  = (size_t)30000 * 600 * 2;   // 36.0 MB
  const size_t aBytes  = (size_t)30080 * 320 * 2;   // 19.3 MB (stays live)
  const size_t btBytes = (size_t)640 * 320 * 2;     // 0.41 MB
  const size_t muBytes = (size_t)256 * 512 * 64 * 2;// 16.8 MB (aliased post-stage1)
  const size_t need = uBytes + aBytes + btBytes + muBytes + ((size_t)8 << 20);
  if (ws_size < need) return;

  __hip_bfloat16* U = (__hip_bfloat16*)take(uBytes);
  ushort* Abf = (ushort*)take(aBytes);
  ushort* BTbf = (ushort*)take(btBytes);
  char* muRegion = (char*)take(muBytes);
  ushort* MuS = (ushort*)muRegion;
  float* hbar_p = (float*)(muRegion + 0);                 // 8*256*608*4 = 4,980,736
  float* Fbar_p = (float*)(muRegion + 4980736);           // 8*256*300*4 = 2,457,600
  float* att_g  = (float*)(muRegion + 7438336);           //   307,200
  float* g2_g   = (float*)(muRegion + 7745536);           //   622,592
  float* hbar_s = (float*)(muRegion + 8675328);           //   622,592
  float* Fbar_s = (float*)(muRegion + 9297920);           //   307,200
  float* att_p  = (float*)(muRegion + 9605120);           // 4*256*300*4 = 1,228,800
  float* g2_p   = (float*)(muRegion + 10833920);          // 4*256*608*4 = 2,490,368
  float* fin_p  = (float*)(muRegion + 13324288);          // 4*256*300*4 = 1,228,800

  float* fsum   = (float*)take(30000*4);
  float* fsq    = (float*)take(30000*4);
  float* gw_g   = (float*)take(600*4);
  float* c_g    = (float*)take(600*4);
  float* sgs_g  = (float*)take(256*300*4);
  float* ssum_g = (float*)take(256*4);
  float* ssq_g  = (float*)take(256*4);
  float* V_g    = (float*)take(256*600*4);
  float* wgt_g  = (float*)take(256*512*4);
  float* m_g    = (float*)take(256*4);
  float* rs_g   = (float*)take(256*4);
  float* cent_p = (float*)take((size_t)2048*64*4);
  float* msum_p = (float*)take(2048*4);
  float* al_g   = (float*)take((size_t)256*512*4);
  float* wsum_p = (float*)take(2048*4);
  float* sgs_p  = (float*)take((size_t)2048*304*4);

  k_pack_stats<<<7520, 256, 0, stream>>>(feat_tab, Abf, fsum, fsq);
  k_pack_b<<<(640*320 + 255)/256, 256, 0, stream>>>(w1, ln1g, BTbf);
  k_gw<<<3, 256, 0, stream>>>(w1, ln1g, ln1b, b1, gw_g, c_g);
  k_ugemm_mfma<<<dim3(235, 5), 256, 0, stream>>>(Abf, BTbf, U);
  k_mu_stage<<<2048, 256, 0, stream>>>(ids_a, mask_a, ids_b, mask_b,
                                       mu_tab, pos_mu, alpha_tab, pos_alpha,
                                       MuS, cent_p, msum_p, al_g);
  k_wrender<<<2048, 256, 0, stream>>>(ids_a, ids_b, logvar_tab, MuS, cent_p, msum_p,
                                      al_g, log_tau, Abf, wsum_p, sgs_p);
  k_stage1c<<<256, 512, 0, stream>>>(ids_a, mask_a, ids_b, mask_b,
                                     MuS, sgs_p, wsum_p,
                                     wq, bq, wk, bk,
                                     sgs_g, ssum_g, ssq_g, wgt_g);
  k_vgemm2<<<dim3(8, 19), 256, 0, stream>>>(sgs_g, w1, ln1g, V_g);
  k_hbar_fbar<<<2048, 256, 0, stream>>>(ids_a, ids_b, U, Abf, fsum, fsq,
                                        ssum_g, ssq_g, V_g, gw_g, c_g, wgt_g,
                                        hbar_p, Fbar_p);
  k_hreduce<<<608, 256, 0, stream>>>(hbar_p, Fbar_p, hbar_s, Fbar_s);
  k_att_sk<<<dim3(8, 10, 4), 256, 0, stream>>>(hbar_s, w2, att_p);
  k_att_stats<<<256, 64, 0, stream>>>(att_p, Fbar_s, b2, ssum_g, ssq_g, att_g, m_g, rs_g);
  k_mlp1_sk<<<dim3(8, 19, 4), 256, 0, stream>>>(sgs_g, att_g, m_g, rs_g, ln2g, ln2b, aw1, g2_p);
  k_mlp1_red<<<608, 256, 0, stream>>>(g2_p, ab1, g2_g);
  k_mlp2_sk<<<dim3(8, 10, 4), 256, 0, stream>>>(g2_g, aw2, fin_p);
  k_mlp2cos<<<128, 64, 0, stream>>>(fin_p, sgs_g, ab2, out);
}

// Round 16
// 249.883 us; speedup vs baseline: 1.0510x; 1.0489x over previous
//
#include <hip/hip_runtime.h>
#include <hip/hip_bf16.h>
#include <cstdint>
#include <cstddef>

#define DEV __device__ __forceinline__

// problem constants: B=128, S=512, V=30000, DS=64, DF=300, H=600, BB=256

typedef __attribute__((ext_vector_type(8))) short bf16x8;
typedef __attribute__((ext_vector_type(4))) float f32x4;

DEV float geluf(float x){ return 0.5f*x*(1.f + erff(x*0.7071067811865475f)); }
DEV float gelu_fast(float x){
  float x2 = x*x;
  float e = __builtin_amdgcn_exp2f(x * __builtin_fmaf(x2, -0.102953f, -2.302218f));
  return x * __builtin_amdgcn_rcpf(1.f + e);
}

DEV float wave_sum(float v){
  v += __shfl_xor(v, 1); v += __shfl_xor(v, 2); v += __shfl_xor(v, 4);
  v += __shfl_xor(v, 8); v += __shfl_xor(v, 16); v += __shfl_xor(v, 32);
  return v;
}
DEV float wave_max(float v){
  v = fmaxf(v, __shfl_xor(v, 1)); v = fmaxf(v, __shfl_xor(v, 2));
  v = fmaxf(v, __shfl_xor(v, 4)); v = fmaxf(v, __shfl_xor(v, 8));
  v = fmaxf(v, __shfl_xor(v, 16)); v = fmaxf(v, __shfl_xor(v, 32));
  return v;
}
DEV float blk_sum512w(float* red8, int t, float v){
  float w = wave_sum(v);
  if ((t & 63) == 0) red8[t >> 6] = w;
  __syncthreads();
  float r = (red8[0] + red8[1]) + (red8[2] + red8[3])
          + (red8[4] + red8[5]) + (red8[6] + red8[7]);
  __syncthreads();
  return r;
}
DEV float blk_max512w(float* red8, int t, float v){
  float w = wave_max(v);
  if ((t & 63) == 0) red8[t >> 6] = w;
  __syncthreads();
  float r = fmaxf(fmaxf(fmaxf(red8[0], red8[1]), fmaxf(red8[2], red8[3])),
                  fmaxf(fmaxf(red8[4], red8[5]), fmaxf(red8[6], red8[7])));
  __syncthreads();
  return r;
}
DEV float blk_sum256(float* red, int t, float v){
  red[t] = v; __syncthreads();
  for (int o = 128; o > 0; o >>= 1){ if (t < o) red[t] += red[t+o]; __syncthreads(); }
  float r = red[0]; __syncthreads(); return r;
}

DEV ushort f2bf(float v){ __hip_bfloat16 h = __float2bfloat16(v); return *(ushort*)&h; }
DEV float bf2f(ushort u){ __hip_bfloat16 h; *(ushort*)&h = u; return __bfloat162float(h); }

// ---- mask dtype classifier ----
DEV int mask_mode(const unsigned char* m){
  bool big = false, off123 = false, off0one = false;
  #pragma unroll
  for (int i = 0; i < 16; ++i){
    unsigned char c = m[i];
    if (c > 1) big = true;
    if ((i & 3) != 0 && c != 0) off123 = true;
    if ((i & 3) == 0 && c == 1) off0one = true;
  }
  if (big) return 2;
  if (!off123 && off0one) return 1;
  return 0;
}
DEV float mask_read(const void* m, int idx, int mode){
  if (mode == 1) return ((const int*)m)[idx] ? 1.f : 0.f;
  if (mode == 2) return ((const unsigned short*)m)[idx] ? 1.f : 0.f;
  return ((const unsigned char*)m)[idx] ? 1.f : 0.f;
}

// ---------------- fused: pack A + per-vocab stats ----------------
__global__ __launch_bounds__(256)
void k_pack_stats(const float* __restrict__ feat, ushort* __restrict__ A,
                  float* __restrict__ fsum, float* __restrict__ fsq){
  int v = blockIdx.x*4 + (threadIdx.x >> 6);
  int ln = threadIdx.x & 63;
  if (v >= 30080) return;
  float vals[8] = {0.f,0.f,0.f,0.f,0.f,0.f,0.f,0.f};
  if (v < 30000 && ln < 38){
    const float* fr = &feat[(size_t)v*300];
    if (ln < 37){
      float4 a = *(const float4*)&fr[ln*8];
      float4 b = *(const float4*)&fr[ln*8 + 4];
      vals[0]=a.x; vals[1]=a.y; vals[2]=a.z; vals[3]=a.w;
      vals[4]=b.x; vals[5]=b.y; vals[6]=b.z; vals[7]=b.w;
    } else {
      float4 a = *(const float4*)&fr[296];
      vals[0]=a.x; vals[1]=a.y; vals[2]=a.z; vals[3]=a.w;
    }
  }
  if (ln < 40){
    union { ushort u[8]; bf16x8 v8; } pk;
    #pragma unroll
    for (int i = 0; i < 8; ++i) pk.u[i] = f2bf(vals[i]);
    *(bf16x8*)&A[(size_t)v*320 + ln*8] = pk.v8;
  }
  float s = 0.f, q = 0.f;
  #pragma unroll
  for (int i = 0; i < 8; ++i){ s += vals[i]; q += vals[i]*vals[i]; }
  for (int o = 32; o > 0; o >>= 1){ s += __shfl_xor(s, o); q += __shfl_xor(q, o); }
  if (ln == 0 && v < 30000){ fsum[v] = s; fsq[v] = q; }
}

// ---------------- P0b: gw1/cv partials (parallel, 24 blocks) ----------------
__global__ __launch_bounds__(256)
void k_gw1_part(const float* __restrict__ w1, const float* __restrict__ g,
                const float* __restrict__ bln, float* __restrict__ pgw, float* __restrict__ pcv){
  int j = blockIdx.x*256 + threadIdx.x;
  int ic = blockIdx.y;
  if (j >= 600) return;
  float a = 0.f, c = 0.f;
  for (int i = ic*75; i < ic*75 + 75; ++i){
    float w = w1[i*600 + j];
    a += g[i]*w; c += bln[i]*w;
  }
  pgw[ic*600 + j] = a; pcv[ic*600 + j] = c;
}

__global__ __launch_bounds__(256)
void k_gw_reduce(const float* __restrict__ pgw, const float* __restrict__ pcv,
                 const float* __restrict__ b1, float* __restrict__ gw_g, float* __restrict__ c_g){
  int j = blockIdx.x*256 + threadIdx.x;
  if (j >= 600) return;
  float a = 0.f, c = 0.f;
  for (int k = 0; k < 8; ++k){ a += pgw[k*600 + j]; c += pcv[k*600 + j]; }
  gw_g[j] = a; c_g[j] = c + b1[j];
}

// ---------------- pack B^T ----------------
__global__ __launch_bounds__(256)
void k_pack_b(const float* __restrict__ w1, const float* __restrict__ g, ushort* __restrict__ BT){
  int id = blockIdx.x*256 + threadIdx.x;
  if (id >= 640*320) return;
  int n = id % 640, k = id / 640;
  float val = (k < 300 && n < 600) ? g[k]*w1[k*600 + n] : 0.f;
  BT[(size_t)n*320 + k] = f2bf(val);
}

// ---------------- P1: U GEMM (MFMA) ----------------
__global__ __launch_bounds__(256)
void k_ugemm_mfma(const ushort* __restrict__ A, const ushort* __restrict__ BT,
                  __hip_bfloat16* __restrict__ U){
  __shared__ ushort As[128][40];
  __shared__ ushort Bs[128][40];
  int tid = threadIdx.x;
  int bm = blockIdx.x * 128, bn = blockIdx.y * 128;
  int wid = tid >> 6, lane = tid & 63;
  int wr = wid >> 1, wc = wid & 1;
  int lr = lane & 15, lk = lane >> 4;
  f32x4 acc[4][4] = {};
  for (int k0 = 0; k0 < 320; k0 += 32){
    #pragma unroll
    for (int j = 0; j < 2; ++j){
      int idx = tid + 256*j;
      int row = idx >> 2, ko = (idx & 3)*8;
      *(bf16x8*)&As[row][ko] = *(const bf16x8*)&A[(size_t)(bm+row)*320 + k0 + ko];
      *(bf16x8*)&Bs[row][ko] = *(const bf16x8*)&BT[(size_t)(bn+row)*320 + k0 + ko];
    }
    __syncthreads();
    bf16x8 af[4], bfr[4];
    #pragma unroll
    for (int f = 0; f < 4; ++f){
      af[f]  = *(const bf16x8*)&As[wr*64 + f*16 + lr][lk*8];
      bfr[f] = *(const bf16x8*)&Bs[wc*64 + f*16 + lr][lk*8];
    }
    #pragma unroll
    for (int i = 0; i < 4; ++i)
      #pragma unroll
      for (int j = 0; j < 4; ++j)
        acc[i][j] = __builtin_amdgcn_mfma_f32_16x16x32_bf16(af[i], bfr[j], acc[i][j], 0, 0, 0);
    __syncthreads();
  }
  #pragma unroll
  for (int i = 0; i < 4; ++i){
    #pragma unroll
    for (int j = 0; j < 4; ++j){
      #pragma unroll
      for (int r = 0; r < 4; ++r){
        int row = bm + wr*64 + i*16 + lk*4 + r;
        int col = bn + wc*64 + j*16 + lr;
        if (row < 30000 && col < 600)
          U[(size_t)row*600 + col] = __float2bfloat16(acc[i][j][r]);
      }
    }
  }
}

// ---------------- S1a: mu gather+stage ----------------
__global__ __launch_bounds__(256)
void k_mu_stage(const int* __restrict__ ids_a, const void* __restrict__ mask_a,
                const int* __restrict__ ids_b, const void* __restrict__ mask_b,
                const float* __restrict__ mu_tab, const float* __restrict__ pos_mu,
                const float* __restrict__ alpha_tab, const float* __restrict__ pos_alpha,
                ushort* __restrict__ MuS, float* __restrict__ cent_p,
                float* __restrict__ msum_p, float* __restrict__ al_g){
  int blk = blockIdx.x;
  int bb = blk >> 3, qr = blk & 7;
  int b = bb & 127;
  const int* ids = (bb < 128) ? ids_a : ids_b;
  const void* msk = (bb < 128) ? mask_a : mask_b;
  int t = threadIdx.x;
  int grp = t >> 4, sub = t & 15;
  __shared__ int mmode_s;
  __shared__ float gpart[16][64];
  __shared__ float mf_s[64];
  __shared__ float red[256];
  if (t == 0) mmode_s = mask_mode((const unsigned char*)msk);
  __syncthreads();
  int mmode = mmode_s;
  float cp0=0.f, cp1=0.f, cp2=0.f, cp3=0.f;
  #pragma unroll
  for (int k = 0; k < 4; ++k){
    int sl = grp*4 + k;
    int s  = qr*64 + sl;
    int id = ids[b*512 + s];
    float mf = mask_read(msk, b*512 + s, mmode);
    float4 m4 = *(const float4*)&mu_tab[(size_t)id*64 + sub*4];
    float4 p4 = *(const float4*)&pos_mu[s*64 + sub*4];
    float v0 = m4.x+p4.x, v1 = m4.y+p4.y, v2 = m4.z+p4.z, v3 = m4.w+p4.w;
    ushort4 st; st.x = f2bf(v0); st.y = f2bf(v1); st.z = f2bf(v2); st.w = f2bf(v3);
    *(ushort4*)&MuS[((size_t)bb*512 + s)*64 + sub*4] = st;
    cp0 += mf*v0; cp1 += mf*v1; cp2 += mf*v2; cp3 += mf*v3;
    if (sub == 0){
      mf_s[sl] = mf;
      float pa = pos_alpha[s];
      float sg = __builtin_amdgcn_rcpf(1.f + __builtin_amdgcn_exp2f(-1.44269504f*pa));
      al_g[bb*512 + s] = alpha_tab[id] * sg * mf;
    }
  }
  gpart[grp][sub*4+0] = cp0; gpart[grp][sub*4+1] = cp1;
  gpart[grp][sub*4+2] = cp2; gpart[grp][sub*4+3] = cp3;
  __syncthreads();
  if (t < 64){
    float c = 0.f;
    #pragma unroll
    for (int g = 0; g < 16; ++g) c += gpart[g][t];
    cent_p[(size_t)blk*64 + t] = c;
  }
  float ms = blk_sum256(red, t, (t < 64) ? mf_s[t] : 0.f);
  if (t == 0) msum_p[blk] = ms;
}

// ---------------- S1c: cent reduce (fused) + w = alpha*K + render partials ----------------
__global__ __launch_bounds__(256)
void k_wrender(const int* __restrict__ ids_a, const int* __restrict__ ids_b,
               const float* __restrict__ logvar_tab, const ushort* __restrict__ MuS,
               const float* __restrict__ cent_p, const float* __restrict__ msum_p,
               const float* __restrict__ al_g,
               const float* __restrict__ log_tau, const ushort* __restrict__ Abf,
               float* __restrict__ wsum_p, float* __restrict__ sgs_p){
  int blk = blockIdx.x;
  int bb = blk >> 3, qr = blk & 7;
  int b = bb & 127;
  const int* ids = (bb < 128) ? ids_a : ids_b;
  int t = threadIdx.x;
  int grp = t >> 4, sub = t & 15;
  __shared__ float cent_s[64];
  __shared__ float wl[64];
  __shared__ int   idl[64];
  __shared__ float pacc[4][304];
  __shared__ float red[256];
  if (t < 64){
    float c = 0.f, ms = 0.f;
    #pragma unroll
    for (int q = 0; q < 8; ++q){
      c  += cent_p[(size_t)(bb*8+q)*64 + t];
      ms += msum_p[bb*8+q];
    }
    cent_s[t] = c / fmaxf(ms, 1.f);
  }
  __syncthreads();
  float itau = __builtin_amdgcn_exp2f(-1.44269504f*log_tau[0]);
  float c0 = cent_s[sub*4+0], c1 = cent_s[sub*4+1];
  float c2 = cent_s[sub*4+2], c3 = cent_s[sub*4+3];
  #pragma unroll
  for (int k = 0; k < 4; ++k){
    int sl = grp*4 + k, s = qr*64 + sl;
    int id = ids[b*512 + s];
    float4 lv = *(const float4*)&logvar_tab[(size_t)id*64 + sub*4];
    float iv0 = __builtin_amdgcn_exp2f(-1.44269504f*lv.x);
    float iv1 = __builtin_amdgcn_exp2f(-1.44269504f*lv.y);
    float iv2 = __builtin_amdgcn_exp2f(-1.44269504f*lv.z);
    float iv3 = __builtin_amdgcn_exp2f(-1.44269504f*lv.w);
    ushort4 mu = *(const ushort4*)&MuS[((size_t)bb*512 + s)*64 + sub*4];
    float d0 = bf2f(mu.x)-c0, d1 = bf2f(mu.y)-c1, d2v = bf2f(mu.z)-c2, d3 = bf2f(mu.w)-c3;
    float val = d0*d0*iv0 + d1*d1*iv1 + d2v*d2v*iv2 + d3*d3*iv3;
    val += __shfl_xor(val, 1); val += __shfl_xor(val, 2);
    val += __shfl_xor(val, 4); val += __shfl_xor(val, 8);
    if (sub == 0){
      idl[sl] = id;
      float K = __builtin_amdgcn_exp2f(-0.72134752f * val * itau);
      wl[sl] = al_g[bb*512 + s] * K;
    }
  }
  __syncthreads();
  float ws = blk_sum256(red, t, (t < 64) ? wl[t] : 0.f);
  if (t == 0) wsum_p[blk] = ws;
  int wv = t >> 6, ln = t & 63;
  if (ln < 38){
    float a[8] = {};
    for (int k = 0; k < 16; ++k){
      int sl = (wv << 4) | k;
      float w = wl[sl];
      bf16x8 f8 = *(const bf16x8*)&Abf[(size_t)idl[sl]*320 + ln*8];
      #pragma unroll
      for (int r = 0; r < 8; ++r) a[r] += w * bf2f((ushort)f8[r]);
    }
    #pragma unroll
    for (int r = 0; r < 8; ++r) pacc[wv][ln*8 + r] = a[r];
  }
  __syncthreads();
  for (int j = t; j < 300; j += 256)
    sgs_p[(size_t)blk*304 + j] = pacc[0][j] + pacc[1][j] + pacc[2][j] + pacc[3][j];
}

// ---------------- S1d: sgs reduce, query, scores, softmax (wave reductions) ----------------
__global__ __launch_bounds__(512)
void k_stage1c(const int* __restrict__ ids_a, const void* __restrict__ mask_a,
               const int* __restrict__ ids_b, const void* __restrict__ mask_b,
               const ushort* __restrict__ MuS, const float* __restrict__ sgs_p,
               const float* __restrict__ wsum_p,
               const float* __restrict__ wq, const float* __restrict__ bq,
               const float* __restrict__ wk, const float* __restrict__ bk,
               float* __restrict__ sgs_g, float* __restrict__ ssum_g, float* __restrict__ ssq_g,
               float* __restrict__ wgt_g)
{
  int bb = blockIdx.x;
  const void* msk = (bb < 128) ? mask_a : mask_b;
  int b = bb & 127;
  int t = threadIdx.x;
  __shared__ float mf_l[512], w_l[512];
  __shared__ float red8[8], red8b[8];
  __shared__ float q_l[64], qk_l[64];
  __shared__ float sgs_l[304];
  __shared__ float bkq_s;
  __shared__ int mmode;
  if (t == 0) mmode = mask_mode((const unsigned char*)msk);
  __syncthreads();
  mf_l[t] = mask_read(msk, b*512 + t, mmode);

  float wsum = 0.f;
  #pragma unroll
  for (int q = 0; q < 8; ++q) wsum += wsum_p[bb*8 + q];
  wsum = fmaxf(wsum, 1e-8f);
  if (t < 300){
    float sa = 0.f;
    #pragma unroll
    for (int q = 0; q < 8; ++q) sa += sgs_p[(size_t)(bb*8+q)*304 + t];
    float sv = sa / wsum;
    sgs_l[t] = sv;
    sgs_g[bb*300 + t] = sv;
  }
  __syncthreads();
  {
    float v1 = (t < 300) ? sgs_l[t] : 0.f;
    float s1 = wave_sum(v1), s2 = wave_sum(v1*v1);
    if ((t & 63) == 0){ red8[t >> 6] = s1; red8b[t >> 6] = s2; }
    __syncthreads();
    if (t == 0){
      float ssum = (red8[0]+red8[1])+(red8[2]+red8[3])+(red8[4]+red8[5])+(red8[6]+red8[7]);
      float ssq  = (red8b[0]+red8b[1])+(red8b[2]+red8b[3])+(red8b[4]+red8b[5])+(red8b[6]+red8b[7]);
      ssum_g[bb] = ssum; ssq_g[bb] = ssq;
    }
  }

  if (t < 64){
    float q = bq[t];
    for (int i = 0; i < 300; ++i) q += sgs_l[i]*wq[i*64 + t];
    q_l[t] = q;
  }
  __syncthreads();
  if (t < 64){
    float a = 0.f;
    for (int j = 0; j < 64; ++j) a += wk[t*64 + j]*q_l[j];
    qk_l[t] = a;
  }
  if (t == 0){
    float s = 0.f;
    for (int j = 0; j < 64; ++j) s += bk[j]*q_l[j];
    bkq_s = s;
  }
  __syncthreads();

  int grp = t >> 4, sub = t & 15;
  {
    float q0 = qk_l[sub*4+0], q1 = qk_l[sub*4+1], q2 = qk_l[sub*4+2], q3 = qk_l[sub*4+3];
    for (int k = 0; k < 16; ++k){
      int s = (grp << 4) | k;
      ushort4 mu = *(const ushort4*)&MuS[((size_t)bb*512 + s)*64 + sub*4];
      float val = bf2f(mu.x)*q0 + bf2f(mu.y)*q1 + bf2f(mu.z)*q2 + bf2f(mu.w)*q3;
      val += __shfl_xor(val, 1); val += __shfl_xor(val, 2);
      val += __shfl_xor(val, 4); val += __shfl_xor(val, 8);
      if (sub == 0){
        float sv = (val + bkq_s) * 0.125f;
        w_l[s] = (mf_l[s] != 0.f) ? sv : -1e30f;
      }
    }
  }
  __syncthreads();

  float mx = blk_max512w(red8, t, w_l[t]);
  float ex = __expf(w_l[t] - mx);
  float Z  = blk_sum512w(red8, t, ex);
  wgt_g[bb*512 + t] = ex / Z;
}

// ---------------- k_vgemm2 ----------------
__global__ __launch_bounds__(256)
void k_vgemm2(const float* __restrict__ sgs, const float* __restrict__ w1,
              const float* __restrict__ ln1g, float* __restrict__ V_g){
  __shared__ float As[32][33], Bs[32][33];
  int t = threadIdx.x;
  int bm = blockIdx.x*32, bn = blockIdx.y*32;
  int tx = t & 15, ty = t >> 4;
  float a00=0.f,a01=0.f,a10=0.f,a11=0.f;
  for (int k0 = 0; k0 < 300; k0 += 32){
    #pragma unroll
    for (int i = 0; i < 4; ++i){
      int idx = t + i*256;
      int kk = idx & 31, m = idx >> 5;
      int kg = k0 + kk;
      As[kk][m] = (kg < 300) ? sgs[(size_t)(bm+m)*300 + kg] : 0.f;
    }
    #pragma unroll
    for (int i = 0; i < 4; ++i){
      int idx = t + i*256;
      int n = idx & 31, kk = idx >> 5;
      int kg = k0 + kk, cg = bn + n;
      Bs[kk][n] = (kg < 300 && cg < 600) ? ln1g[300 + kg]*w1[(size_t)(300 + kg)*600 + cg] : 0.f;
    }
    __syncthreads();
    #pragma unroll
    for (int kk = 0; kk < 32; ++kk){
      float x0 = As[kk][ty*2], x1 = As[kk][ty*2+1];
      float y0 = Bs[kk][tx*2], y1 = Bs[kk][tx*2+1];
      a00 += x0*y0; a01 += x0*y1; a10 += x1*y0; a11 += x1*y1;
    }
    __syncthreads();
  }
  int r0 = bm + ty*2, c0 = bn + tx*2;
  #pragma unroll
  for (int i = 0; i < 2; ++i){
    #pragma unroll
    for (int j = 0; j < 2; ++j){
      int r = r0 + i, c = c0 + j;
      if (c < 600) V_g[(size_t)r*600 + c] = (i==0 ? (j==0?a00:a01) : (j==0?a10:a11));
    }
  }
}

// ---------------- K2: hbar + Fbar eighth-split (balanced tail) ----------------
__global__ __launch_bounds__(256)
void k_hbar_fbar(const int* __restrict__ ids_a, const int* __restrict__ ids_b,
                 const __hip_bfloat16* __restrict__ U, const ushort* __restrict__ Abf,
                 const float* __restrict__ fsum, const float* __restrict__ fsq,
                 const float* __restrict__ ssum_g, const float* __restrict__ ssq_g,
                 const float* __restrict__ V_g, const float* __restrict__ gw_g,
                 const float* __restrict__ c_g, const float* __restrict__ wgt_g,
                 float* __restrict__ hbar_p, float* __restrict__ Fbar_p)
{
  int blk = blockIdx.x;
  int bb = blk >> 3, qr = blk & 7;
  int b = bb & 127;
  const int* ids = (bb < 128) ? ids_a : ids_b;
  int t = threadIdx.x;
  __shared__ int id_l[64];
  __shared__ float m_l[64], rs_l[64], wg_l[64];
  __shared__ float hp[4][600];
  __shared__ float fp[4][304];
  float ss = ssum_g[bb], sq = ssq_g[bb];
  if (t < 64){
    int s = qr*64 + t;
    int id = ids[b*512 + s];
    id_l[t] = id;
    float m = (fsum[id] + ss) * (1.f/600.f);
    float var = (fsq[id] + sq) * (1.f/600.f) - m*m;
    m_l[t] = m;
    rs_l[t] = 1.f / sqrtf(var + 1e-5f);
    wg_l[t] = wgt_g[bb*512 + s];
  }
  __syncthreads();

  int wv = t >> 6, ln = t & 63;
  float Vp[8], gwp[8], cp[8];
  #pragma unroll
  for (int r = 0; r < 8; ++r){
    int j = ln*8 + r;
    Vp[r] = V_g[bb*600 + j]; gwp[r] = gw_g[j]; cp[r] = c_g[j];
  }
  float Vs[4] = {}, gws[4] = {}, cs[4] = {};
  if (ln < 22){
    #pragma unroll
    for (int r = 0; r < 4; ++r){
      int j = 512 + ln*4 + r;
      Vs[r] = V_g[bb*600 + j]; gws[r] = gw_g[j]; cs[r] = c_g[j];
    }
  }
  float h1[8] = {}, h2[4] = {}, fa[8] = {};

  for (int k = 0; k < 16; ++k){
    int s = (wv << 4) | k;
    int id = id_l[s];
    float w = wg_l[s], m = m_l[s], rs = rs_l[s];
    const __hip_bfloat16* ur = &U[(size_t)id*600];
    bf16x8 u8 = *(const bf16x8*)&ur[ln*8];
    #pragma unroll
    for (int r = 0; r < 8; ++r){
      float u = bf2f((ushort)u8[r]);
      float a = (u + Vp[r] - m*gwp[r])*rs + cp[r];
      h1[r] += w*gelu_fast(a);
    }
    if (ln < 22){
      ushort4 u4 = *(const ushort4*)&ur[512 + ln*4];
      float uu[4] = { bf2f(u4.x), bf2f(u4.y), bf2f(u4.z), bf2f(u4.w) };
      #pragma unroll
      for (int r = 0; r < 4; ++r){
        float a = (uu[r] + Vs[r] - m*gws[r])*rs + cs[r];
        h2[r] += w*gelu_fast(a);
      }
    }
    if (ln < 38){
      bf16x8 f8 = *(const bf16x8*)&Abf[(size_t)id*320 + ln*8];
      #pragma unroll
      for (int r = 0; r < 8; ++r) fa[r] += w * bf2f((ushort)f8[r]);
    }
  }
  #pragma unroll
  for (int r = 0; r < 8; ++r) hp[wv][ln*8 + r] = h1[r];
  if (ln < 22){
    #pragma unroll
    for (int r = 0; r < 4; ++r) hp[wv][512 + ln*4 + r] = h2[r];
  }
  if (ln < 38){
    #pragma unroll
    for (int r = 0; r < 8; ++r) fp[wv][ln*8 + r] = fa[r];
  }
  __syncthreads();
  size_t hbase = ((size_t)qr*256 + bb)*608;
  for (int j = t; j < 600; j += 256){
    hbar_p[hbase + j] = hp[0][j] + hp[1][j] + hp[2][j] + hp[3][j];
  }
  if (t < 8) hbar_p[hbase + 600 + t] = 0.f;
  size_t fbase = ((size_t)qr*256 + bb)*300;
  for (int j = t; j < 300; j += 256){
    Fbar_p[fbase + j] = fp[0][j] + fp[1][j] + fp[2][j] + fp[3][j];
  }
}

// ---------------- k_hreduce ----------------
__global__ __launch_bounds__(256)
void k_hreduce(const float* __restrict__ hbar_p, const float* __restrict__ Fbar_p,
               float* __restrict__ hbar_s, float* __restrict__ Fbar_s){
  int i = blockIdx.x*256 + threadIdx.x;
  const size_t Q  = (size_t)256*608;
  const size_t QF = (size_t)256*300;
  if (i < 256*608){
    float s0 = hbar_p[i]       + hbar_p[Q + i];
    float s1 = hbar_p[2*Q + i] + hbar_p[3*Q + i];
    float s2 = hbar_p[4*Q + i] + hbar_p[5*Q + i];
    float s3 = hbar_p[6*Q + i] + hbar_p[7*Q + i];
    hbar_s[i] = (s0 + s1) + (s2 + s3);
  }
  if (i < 256*300){
    float s0 = Fbar_p[i]        + Fbar_p[QF + i];
    float s1 = Fbar_p[2*QF + i] + Fbar_p[3*QF + i];
    float s2 = Fbar_p[4*QF + i] + Fbar_p[5*QF + i];
    float s3 = Fbar_p[6*QF + i] + Fbar_p[7*QF + i];
    Fbar_s[i] = (s0 + s1) + (s2 + s3);
  }
}

// ============ final chain: split-K tiled fp32 GEMMs ============

__global__ __launch_bounds__(256)
void k_att_sk(const float* __restrict__ hbar_s, const float* __restrict__ w2,
              float* __restrict__ att_p){
  __shared__ float As[32][33], Bs[32][33];
  int t = threadIdx.x;
  int bm = blockIdx.x*32, bn = blockIdx.y*32, kc = blockIdx.z;
  int tx = t & 15, ty = t >> 4;
  int kbeg = kc*160, kend = (kc == 3) ? 608 : kbeg + 160;
  float a00=0.f,a01=0.f,a10=0.f,a11=0.f;
  for (int k0 = kbeg; k0 < kend; k0 += 32){
    #pragma unroll
    for (int i = 0; i < 4; ++i){
      int idx = t + i*256;
      int kk = idx & 31, m = idx >> 5;
      As[kk][m] = hbar_s[(size_t)(bm+m)*608 + k0 + kk];
    }
    #pragma unroll
    for (int i = 0; i < 4; ++i){
      int idx = t + i*256;
      int n = idx & 31, kk = idx >> 5;
      int kg = k0 + kk, cg = bn + n;
      Bs[kk][n] = (kg < 600 && cg < 300) ? w2[(size_t)kg*300 + cg] : 0.f;
    }
    __syncthreads();
    #pragma unroll
    for (int kk = 0; kk < 32; ++kk){
      float x0 = As[kk][ty*2], x1 = As[kk][ty*2+1];
      float y0 = Bs[kk][tx*2], y1 = Bs[kk][tx*2+1];
      a00 += x0*y0; a01 += x0*y1; a10 += x1*y0; a11 += x1*y1;
    }
    __syncthreads();
  }
  float* outp = att_p + (size_t)kc*256*300;
  int r0 = bm + ty*2, c0 = bn + tx*2;
  #pragma unroll
  for (int i = 0; i < 2; ++i){
    #pragma unroll
    for (int j = 0; j < 2; ++j){
      int r = r0 + i, c = c0 + j;
      if (c < 300)
        outp[(size_t)r*300 + c] = (i==0 ? (j==0?a00:a01) : (j==0?a10:a11));
    }
  }
}

__global__ __launch_bounds__(64)
void k_att_stats(const float* __restrict__ att_p, const float* __restrict__ Fbar_s,
                 const float* __restrict__ b2, const float* __restrict__ ssum_g,
                 const float* __restrict__ ssq_g,
                 float* __restrict__ att, float* __restrict__ m_g, float* __restrict__ rs_g){
  int bb = blockIdx.x, lane = threadIdx.x;
  const size_t Q = (size_t)256*300;
  float s = 0.f, q = 0.f;
  for (int j = lane; j < 300; j += 64){
    size_t i = (size_t)bb*300 + j;
    float v = (att_p[i] + att_p[Q+i]) + (att_p[2*Q+i] + att_p[3*Q+i]);
    v += b2[j] + Fbar_s[i];
    att[i] = v;
    s += v; q += v*v;
  }
  for (int o = 32; o > 0; o >>= 1){ s += __shfl_xor(s, o); q += __shfl_xor(q, o); }
  if (lane == 0){
    float m = (ssum_g[bb] + s) * (1.f/600.f);
    float var = (ssq_g[bb] + q) * (1.f/600.f) - m*m;
    m_g[bb] = m;
    rs_g[bb] = 1.f / sqrtf(var + 1e-5f);
  }
}

__global__ __launch_bounds__(256)
void k_mlp1_sk(const float* __restrict__ sgs, const float* __restrict__ att,
               const float* __restrict__ m_g, const float* __restrict__ rs_g,
               const float* __restrict__ ln2g, const float* __restrict__ ln2b,
               const float* __restrict__ aw1, float* __restrict__ g2_p){
  __shared__ float As[32][33], Bs[32][33];
  int t = threadIdx.x;
  int bm = blockIdx.x*32, bn = blockIdx.y*32, kc = blockIdx.z;
  int tx = t & 15, ty = t >> 4;
  int kbeg = kc*160, kend = (kc == 3) ? 608 : kbeg + 160;
  float a00=0.f,a01=0.f,a10=0.f,a11=0.f;
  for (int k0 = kbeg; k0 < kend; k0 += 32){
    #pragma unroll
    for (int i = 0; i < 4; ++i){
      int idx = t + i*256;
      int kk = idx & 31, m = idx >> 5;
      int kg = k0 + kk, row = bm + m;
      float t2 = 0.f;
      if (kg < 600){
        float x = (kg < 300) ? sgs[(size_t)row*300 + kg] : att[(size_t)row*300 + kg - 300];
        t2 = (x - m_g[row])*rs_g[row]*ln2g[kg] + ln2b[kg];
      }
      As[kk][m] = t2;
    }
    #pragma unroll
    for (int i = 0; i < 4; ++i){
      int idx = t + i*256;
      int n = idx & 31, kk = idx >> 5;
      int kg = k0 + kk, cg = bn + n;
      Bs[kk][n] = (kg < 600 && cg < 600) ? aw1[(size_t)kg*600 + cg] : 0.f;
    }
    __syncthreads();
    #pragma unroll
    for (int kk = 0; kk < 32; ++kk){
      float x0 = As[kk][ty*2], x1 = As[kk][ty*2+1];
      float y0 = Bs[kk][tx*2], y1 = Bs[kk][tx*2+1];
      a00 += x0*y0; a01 += x0*y1; a10 += x1*y0; a11 += x1*y1;
    }
    __syncthreads();
  }
  float* outp = g2_p + (size_t)kc*256*608;
  int r0 = bm + ty*2, c0 = bn + tx*2;
  #pragma unroll
  for (int i = 0; i < 2; ++i){
    #pragma unroll
    for (int j = 0; j < 2; ++j){
      int r = r0 + i, c = c0 + j;
      outp[(size_t)r*608 + c] = (i==0 ? (j==0?a00:a01) : (j==0?a10:a11));
    }
  }
}

__global__ __launch_bounds__(256)
void k_mlp1_red(const float* __restrict__ g2_p, const float* __restrict__ ab1,
                float* __restrict__ g2){
  int i = blockIdx.x*256 + threadIdx.x;
  if (i >= 256*608) return;
  const size_t Q = (size_t)256*608;
  int c = i % 608;
  float s = (g2_p[i] + g2_p[Q+i]) + (g2_p[2*Q+i] + g2_p[3*Q+i]);
  g2[i] = (c < 600) ? geluf(s + ab1[c]) : 0.f;
}

__global__ __launch_bounds__(256)
void k_mlp2_sk(const float* __restrict__ g2, const float* __restrict__ aw2,
               float* __restrict__ fin_p){
  __shared__ float As[32][33], Bs[32][33];
  int t = threadIdx.x;
  int bm = blockIdx.x*32, bn = blockIdx.y*32, kc = blockIdx.z;
  int tx = t & 15, ty = t >> 4;
  int kbeg = kc*160, kend = (kc == 3) ? 608 : kbeg + 160;
  float a00=0.f,a01=0.f,a10=0.f,a11=0.f;
  for (int k0 = kbeg; k0 < kend; k0 += 32){
    #pragma unroll
    for (int i = 0; i < 4; ++i){
      int idx = t + i*256;
      int kk = idx & 31, m = idx >> 5;
      As[kk][m] = g2[(size_t)(bm+m)*608 + k0 + kk];
    }
    #pragma unroll
    for (int i = 0; i < 4; ++i){
      int idx = t + i*256;
      int n = idx & 31, kk = idx >> 5;
      int kg = k0 + kk, cg = bn + n;
      Bs[kk][n] = (kg < 600 && cg < 300) ? aw2[(size_t)kg*300 + cg] : 0.f;
    }
    __syncthreads();
    #pragma unroll
    for (int kk = 0; kk < 32; ++kk){
      float x0 = As[kk][ty*2], x1 = As[kk][ty*2+1];
      float y0 = Bs[kk][tx*2], y1 = Bs[kk][tx*2+1];
      a00 += x0*y0; a01 += x0*y1; a10 += x1*y0; a11 += x1*y1;
    }
    __syncthreads();
  }
  float* outp = fin_p + (size_t)kc*256*300;
  int r0 = bm + ty*2, c0 = bn + tx*2;
  #pragma unroll
  for (int i = 0; i < 2; ++i){
    #pragma unroll
    for (int j = 0; j < 2; ++j){
      int r = r0 + i, c = c0 + j;
      if (c < 300)
        outp[(size_t)r*300 + c] = (i==0 ? (j==0?a00:a01) : (j==0?a10:a11));
    }
  }
}

__global__ __launch_bounds__(64)
void k_mlp2cos(const float* __restrict__ fin_p, const float* __restrict__ sgs,
               const float* __restrict__ ab2, float* __restrict__ out){
  int b = blockIdx.x, lane = threadIdx.x;
  const size_t Q = (size_t)256*300;
  float dot = 0.f, na = 0.f, nb = 0.f;
  for (int j = lane; j < 300; j += 64){
    size_t ia = (size_t)b*300 + j;
    size_t ib = (size_t)(128 + b)*300 + j;
    float xa = (fin_p[ia] + fin_p[Q+ia]) + (fin_p[2*Q+ia] + fin_p[3*Q+ia]);
    xa += ab2[j] + sgs[ia];
    float xb = (fin_p[ib] + fin_p[Q+ib]) + (fin_p[2*Q+ib] + fin_p[3*Q+ib]);
    xb += ab2[j] + sgs[ib];
    dot += xa*xb; na += xa*xa; nb += xb*xb;
  }
  for (int o = 32; o > 0; o >>= 1){
    dot += __shfl_xor(dot, o); na += __shfl_xor(na, o); nb += __shfl_xor(nb, o);
  }
  if (lane == 0){
    float den = fmaxf(sqrtf(na), 1e-8f) * fmaxf(sqrtf(nb), 1e-8f);
    out[b] = 5.f * dot / den;
  }
}

extern "C" void kernel_launch(void* const* d_in, const int* in_sizes, int n_in,
                              void* d_out, int out_size, void* d_ws, size_t ws_size,
                              hipStream_t stream) {
  const int* ids_a = (const int*)d_in[0];
  const void* mask_a = d_in[1];
  const int* ids_b = (const int*)d_in[2];
  const void* mask_b = d_in[3];
  const float* mu_tab     = (const float*)d_in[4];
  const float* logvar_tab = (const float*)d_in[5];
  const float* alpha_tab  = (const float*)d_in[6];
  const float* feat_tab   = (const float*)d_in[7];
  const float* log_tau    = (const float*)d_in[8];
  const float* pos_mu     = (const float*)d_in[9];
  const float* pos_alpha  = (const float*)d_in[10];
  const float* ln1g = (const float*)d_in[11];
  const float* ln1b = (const float*)d_in[12];
  const float* w1   = (const float*)d_in[13];
  const float* b1   = (const float*)d_in[14];
  const float* w2   = (const float*)d_in[15];
  const float* b2   = (const float*)d_in[16];
  const float* wq   = (const float*)d_in[17];
  const float* bq   = (const float*)d_in[18];
  const float* wk   = (const float*)d_in[19];
  const float* bk   = (const float*)d_in[20];
  const float* ln2g = (const float*)d_in[21];
  const float* ln2b = (const float*)d_in[22];
  const float* aw1  = (const float*)d_in[23];
  const float* ab1  = (const float*)d_in[24];
  const float* aw2  = (const float*)d_in[25];
  const float* ab2  = (const float*)d_in[26];
  float* out = (float*)d_out;

  char* wsb = (char*)d_ws;
  size_t off = 0;
  auto take = [&](size_t bytes) -> void* {
    void* p = wsb + off;
    off += (bytes + 255) & ~(size_t)255;
    return p;
  };

  const size_t uBytes  = (size_t)30000 * 600 * 2;   // 36.0 MB
  const size_t aBytes  = (size_t)30080 * 320 * 2;   // 19.3 MB (stays live)
  const size_t btBytes = (size_t)640 * 320 * 2;     // 0.41 MB
  const size_t muBytes = (size_t)256 * 512 * 64 * 2;// 16.8 MB (aliased post-stage1)
  const size_t need = uBytes + aBytes + btBytes + muBytes + ((size_t)8 << 20);
  if (ws_size < need) return;

  __hip_bfloat16* U = (__hip_bfloat16*)take(uBytes);
  ushort* Abf = (ushort*)take(aBytes);
  ushort* BTbf = (ushort*)take(btBytes);
  char* muRegion = (char*)take(muBytes);
  ushort* MuS = (ushort*)muRegion;
  float* hbar_p = (float*)(muRegion + 0);                 // 8*256*608*4 = 4,980,736
  float* Fbar_p = (float*)(muRegion + 4980736);           // 8*256*300*4 = 2,457,600
  float* att_g  = (float*)(muRegion + 7438336);           //   307,200
  float* g2_g   = (float*)(muRegion + 7745536);           //   622,592
  float* hbar_s = (float*)(muRegion + 8675328);           //   622,592
  float* Fbar_s = (float*)(muRegion + 9297920);           //   307,200
  float* att_p  = (float*)(muRegion + 9605120);           // 4*256*300*4 = 1,228,800
  float* g2_p   = (float*)(muRegion + 10833920);          // 4*256*608*4 = 2,490,368
  float* fin_p  = (float*)(muRegion + 13324288);          // 4*256*300*4 = 1,228,800

  float* fsum   = (float*)take(30000*4);
  float* fsq    = (float*)take(30000*4);
  float* pgw    = (float*)take(8*600*4);
  float* pcv    = (float*)take(8*600*4);
  float* gw_g   = (float*)take(600*4);
  float* c_g    = (float*)take(600*4);
  float* sgs_g  = (float*)take(256*300*4);
  float* ssum_g = (float*)take(256*4);
  float* ssq_g  = (float*)take(256*4);
  float* V_g    = (float*)take(256*600*4);
  float* wgt_g  = (float*)take(256*512*4);
  float* m_g    = (float*)take(256*4);
  float* rs_g   = (float*)take(256*4);
  float* cent_p = (float*)take((size_t)2048*64*4);
  float* msum_p = (float*)take(2048*4);
  float* al_g   = (float*)take((size_t)256*512*4);
  float* wsum_p = (float*)take(2048*4);
  float* sgs_p  = (float*)take((size_t)2048*304*4);

  k_pack_stats<<<7520, 256, 0, stream>>>(feat_tab, Abf, fsum, fsq);
  k_pack_b<<<(640*320 + 255)/256, 256, 0, stream>>>(w1, ln1g, BTbf);
  k_gw1_part<<<dim3(3, 8), 256, 0, stream>>>(w1, ln1g, ln1b, pgw, pcv);
  k_gw_reduce<<<3, 256, 0, stream>>>(pgw, pcv, b1, gw_g, c_g);
  k_ugemm_mfma<<<dim3(235, 5), 256, 0, stream>>>(Abf, BTbf, U);
  k_mu_stage<<<2048, 256, 0, stream>>>(ids_a, mask_a, ids_b, mask_b,
                                       mu_tab, pos_mu, alpha_tab, pos_alpha,
                                       MuS, cent_p, msum_p, al_g);
  k_wrender<<<2048, 256, 0, stream>>>(ids_a, ids_b, logvar_tab, MuS, cent_p, msum_p,
                                      al_g, log_tau, Abf, wsum_p, sgs_p);
  k_stage1c<<<256, 512, 0, stream>>>(ids_a, mask_a, ids_b, mask_b,
                                     MuS, sgs_p, wsum_p,
                                     wq, bq, wk, bk,
                                     sgs_g, ssum_g, ssq_g, wgt_g);
  k_vgemm2<<<dim3(8, 19), 256, 0, stream>>>(sgs_g, w1, ln1g, V_g);
  k_hbar_fbar<<<2048, 256, 0, stream>>>(ids_a, ids_b, U, Abf, fsum, fsq,
                                        ssum_g, ssq_g, V_g, gw_g, c_g, wgt_g,
                                        hbar_p, Fbar_p);
  k_hreduce<<<608, 256, 0, stream>>>(hbar_p, Fbar_p, hbar_s, Fbar_s);
  k_att_sk<<<dim3(8, 10, 4), 256, 0, stream>>>(hbar_s, w2, att_p);
  k_att_stats<<<256, 64, 0, stream>>>(att_p, Fbar_s, b2, ssum_g, ssq_g, att_g, m_g, rs_g);
  k_mlp1_sk<<<dim3(8, 19, 4), 256, 0, stream>>>(sgs_g, att_g, m_g, rs_g, ln2g, ln2b, aw1, g2_p);
  k_mlp1_red<<<608, 256, 0, stream>>>(g2_p, ab1, g2_g);
  k_mlp2_sk<<<dim3(8, 10, 4), 256, 0, stream>>>(g2_g, aw2, fin_p);
  k_mlp2cos<<<128, 64, 0, stream>>>(fin_p, sgs_g, ab2, out);
}